// Round 6
// baseline (629.640 us; speedup 1.0000x reference)
//
#include <hip/hip_runtime.h>
#include <stdint.h>

#define D 128
#define SCAN_TILE 1024  // elements per scan block (256 thr x 4)

typedef __attribute__((ext_vector_type(8))) short bf16x8_t;
typedef __attribute__((ext_vector_type(4))) float f32x4_t;

__device__ inline unsigned short f2bf(float x) {
    unsigned int u = __float_as_uint(x);
    unsigned int r = (u + 0x7fffu + ((u >> 16) & 1u)) >> 16;   // RNE
    return (unsigned short)r;
}
__device__ inline float bflo(unsigned v) { return __uint_as_float(v << 16); }
__device__ inline float bfhi(unsigned v) { return __uint_as_float(v & 0xffff0000u); }

// ---------------------------------------------------------------------------
// f32 -> bf16 bulk convert (8 elems/thread/iter, 16B stores)
// ---------------------------------------------------------------------------
__global__ __launch_bounds__(256) void f32_to_bf16_kernel(
        const float* __restrict__ in, unsigned short* __restrict__ out, int n8) {
    int stride = gridDim.x * blockDim.x;
    for (int i = blockIdx.x * blockDim.x + threadIdx.x; i < n8; i += stride) {
        float4 v0 = *(const float4*)(in + (size_t)i * 8);
        float4 v1 = *(const float4*)(in + (size_t)i * 8 + 4);
        uint4 o;
        o.x = f2bf(v0.x) | ((unsigned)f2bf(v0.y) << 16);
        o.y = f2bf(v0.z) | ((unsigned)f2bf(v0.w) << 16);
        o.z = f2bf(v1.x) | ((unsigned)f2bf(v1.y) << 16);
        o.w = f2bf(v1.z) | ((unsigned)f2bf(v1.w) << 16);
        *(uint4*)(out + (size_t)i * 8) = o;
    }
}

// ---------------------------------------------------------------------------
// deg histogram
// ---------------------------------------------------------------------------
__global__ void count_deg_kernel(const int* __restrict__ ea, const int* __restrict__ ep,
                                 int E, int* __restrict__ degA, int* __restrict__ degP) {
    int stride = gridDim.x * blockDim.x;
    for (int e = blockIdx.x * blockDim.x + threadIdx.x; e < E; e += stride) {
        atomicAdd(&degA[ea[e]], 1);
        atomicAdd(&degP[ep[e]], 1);
    }
}

// ---------------------------------------------------------------------------
// 3-pass device-wide exclusive scan over BOTH deg arrays
// ---------------------------------------------------------------------------
__global__ __launch_bounds__(256) void scan_partials_kernel(
        const int* __restrict__ degA, int nA,
        const int* __restrict__ degP, int nP, int gA,
        int* __restrict__ partials) {
    const int* deg; int n;
    int b = blockIdx.x;
    if (b < gA) { deg = degA; n = nA; }
    else        { deg = degP; n = nP; b -= gA; }
    int tid = threadIdx.x;
    int i0 = b * SCAN_TILE + tid * 4;
    int s = 0;
    if (i0 + 3 < n) {
        int4 d = *(const int4*)(deg + i0);
        s = d.x + d.y + d.z + d.w;
    } else {
        for (int j = 0; j < 4; ++j) if (i0 + j < n) s += deg[i0 + j];
    }
#pragma unroll
    for (int off = 32; off; off >>= 1) s += __shfl_xor(s, off);
    __shared__ int wsum[4];
    if ((tid & 63) == 0) wsum[tid >> 6] = s;
    __syncthreads();
    if (tid == 0) partials[blockIdx.x] = wsum[0] + wsum[1] + wsum[2] + wsum[3];
}

__global__ __launch_bounds__(1024) void scan_block_sums_kernel(
        int* __restrict__ partials, int gA, int gP,
        int* __restrict__ rsA_end, int* __restrict__ rsP_end) {
    __shared__ int s[1024];
    int n = gA + gP;
    int tid = threadIdx.x;
    int v = (tid < n) ? partials[tid] : 0;
    s[tid] = v;
    __syncthreads();
    for (int off = 1; off < 1024; off <<= 1) {
        int add = 0;
        if (tid >= off && ((tid < gA) || (tid - off >= gA))) add = s[tid - off];
        __syncthreads();
        s[tid] += add;
        __syncthreads();
    }
    if (tid == gA - 1)  *rsA_end = s[tid];
    if (tid == n - 1)   *rsP_end = s[tid];
    if (tid < n) partials[tid] = s[tid] - v;
}

__global__ __launch_bounds__(256) void scan_write_kernel(
        const int* __restrict__ degA, int nA, int* __restrict__ rsA,
        const int* __restrict__ degP, int nP, int* __restrict__ rsP,
        int gA, const int* __restrict__ partials) {
    const int* deg; int n; int* rs;
    int b = blockIdx.x;
    int part = partials[blockIdx.x];
    if (b < gA) { deg = degA; n = nA; rs = rsA; }
    else        { deg = degP; n = nP; rs = rsP; b -= gA; }
    int tid = threadIdx.x;
    int lane = tid & 63, wid = tid >> 6;
    int i0 = b * SCAN_TILE + tid * 4;

    int4 d = make_int4(0, 0, 0, 0);
    if (i0 + 3 < n) {
        d = *(const int4*)(deg + i0);
    } else {
        if (i0 + 0 < n) d.x = deg[i0 + 0];
        if (i0 + 1 < n) d.y = deg[i0 + 1];
        if (i0 + 2 < n) d.z = deg[i0 + 2];
        if (i0 + 3 < n) d.w = deg[i0 + 3];
    }
    int tsum = d.x + d.y + d.z + d.w;

    int x = tsum;
#pragma unroll
    for (int off = 1; off < 64; off <<= 1) {
        int y = __shfl_up(x, off);
        if (lane >= off) x += y;
    }
    int excl = x - tsum;

    __shared__ int wsum[4];
    if (lane == 63) wsum[wid] = x;
    __syncthreads();
    int woff = 0;
#pragma unroll
    for (int w = 0; w < 4; ++w) if (w < wid) woff += wsum[w];

    int off0 = part + woff + excl;
    int4 o;
    o.x = off0;
    o.y = off0 + d.x;
    o.z = o.y + d.y;
    o.w = o.z + d.z;
    if (i0 + 3 < n) {
        *(int4*)(rs + i0) = o;
    } else {
        if (i0 + 0 < n) rs[i0 + 0] = o.x;
        if (i0 + 1 < n) rs[i0 + 1] = o.y;
        if (i0 + 2 < n) rs[i0 + 2] = o.z;
        if (i0 + 3 < n) rs[i0 + 3] = o.w;
    }
}

// ---------------------------------------------------------------------------
// bucket cursor init: bcur[b] = rs[b*64]  (bucket = 64 consecutive dst nodes)
// ---------------------------------------------------------------------------
__global__ __launch_bounds__(256) void bcur_init_kernel(
        const int* __restrict__ rsA, int nbA, int* __restrict__ bcurA,
        const int* __restrict__ rsP, int nbP, int* __restrict__ bcurP) {
    int i = blockIdx.x * blockDim.x + threadIdx.x;
    if (i < nbA) bcurA[i] = rsA[i << 6];
    int j = i - nbA;
    if (j >= 0 && j < nbP) bcurP[j] = rsP[j << 6];
}

// ---------------------------------------------------------------------------
// phase B: scatter packed edge entries into per-bucket regions.
// Entry = (src<<6) | (dst&63); src < 2^18 so it fits 24 bits.
// Writes within a bucket are sequential in address and clustered in time
// -> dense 64B lines (kills the 16x write amplification of direct csr fill).
// ---------------------------------------------------------------------------
__global__ __launch_bounds__(256) void bucket_scatter_kernel(
        const int* __restrict__ ea, const int* __restrict__ ep, int E,
        int* __restrict__ bcurA, int* __restrict__ bcurP,
        unsigned* __restrict__ bufA, unsigned* __restrict__ bufP) {
    int stride = gridDim.x * blockDim.x;
    for (int e = blockIdx.x * blockDim.x + threadIdx.x; e < E; e += stride) {
        int a = ea[e], p = ep[e];
        int pa = atomicAdd(&bcurA[a >> 6], 1);
        bufA[pa] = ((unsigned)p << 6) | (unsigned)(a & 63);
        int pp = atomicAdd(&bcurP[p >> 6], 1);
        bufP[pp] = ((unsigned)a << 6) | (unsigned)(p & 63);
    }
}

// ---------------------------------------------------------------------------
// phase C: one block per bucket; LDS per-dst cursors; scatter src into the
// bucket's contiguous csr region (dense, L2-hot writes).
// ---------------------------------------------------------------------------
__global__ __launch_bounds__(256) void bucket_to_csr_kernel(
        const int* __restrict__ rsA, const unsigned* __restrict__ bufA,
        int nA, int nbA, int* __restrict__ csrA,
        const int* __restrict__ rsP, const unsigned* __restrict__ bufP,
        int nP, int nbP, int* __restrict__ csrP) {
    const int* rs; const unsigned* buf; int* csr; int n;
    int b = blockIdx.x;
    if (b < nbA) { rs = rsA; buf = bufA; csr = csrA; n = nA; }
    else         { b -= nbA; rs = rsP; buf = bufP; csr = csrP; n = nP; }
    int d0 = b << 6;
    int nd = n - d0; if (nd > 64) nd = 64;

    __shared__ int base[65];
    __shared__ int cnt[64];
    int tid = threadIdx.x;
    if (tid <= nd) base[tid] = rs[d0 + tid];
    if (tid < nd) cnt[tid] = 0;
    __syncthreads();

    int e0 = base[0], e1 = base[nd];
    for (int j = e0 + tid; j < e1; j += 256) {
        unsigned pk = buf[j];
        int li = pk & 63u;
        int src = (int)(pk >> 6);
        int pos = base[li] + atomicAdd(&cnt[li], 1);
        csr[pos] = src;
    }
}

// ---------------------------------------------------------------------------
// W pre-pack (unchanged): Bcat=[Ws;Wm] -> bf16 MFMA fragment order
// ---------------------------------------------------------------------------
__global__ __launch_bounds__(256) void pack_w_kernel(
        const float* __restrict__ WsA, const float* __restrict__ WsP,
        const float* __restrict__ Wa2p, const float* __restrict__ Wp2a,
        unsigned short* __restrict__ Bpack) {
    int combo = blockIdx.x >> 4;
    int e = (blockIdx.x & 15) * 256 + threadIdx.x;   // 0..4095
    int layer = combo >> 1;
    const float* Ws = ((combo & 1) ? WsP : WsA) + (size_t)layer * D * D;
    const float* Wm = ((combo & 1) ? Wa2p : Wp2a) + (size_t)layer * D * D;

    int f = e >> 6, lane = e & 63;
    int nf = f >> 3, ks = f & 7;
    int k0 = ks * 32 + (lane >> 4) * 8;
    int col = nf * 16 + (lane & 15);

    unsigned short v[8];
#pragma unroll
    for (int j = 0; j < 8; ++j) {
        int k = k0 + j;
        float x = (k < D) ? Ws[(size_t)k * D + col] : Wm[(size_t)(k - D) * D + col];
        v[j] = f2bf(x);
    }
    uint4 o;
    o.x = v[0] | ((unsigned)v[1] << 16);
    o.y = v[2] | ((unsigned)v[3] << 16);
    o.z = v[4] | ((unsigned)v[5] << 16);
    o.w = v[6] | ((unsigned)v[7] << 16);
    *(uint4*)(Bpack + (size_t)combo * 32768 + (size_t)e * 8) = o;
}

// ---------------------------------------------------------------------------
// bf16 pull-aggregation (unchanged): one wave per dst row, 4x16-lane subwaves
// ---------------------------------------------------------------------------
__global__ __launch_bounds__(256) void aggregate_bf16_kernel(
        const unsigned short* __restrict__ xsrc, const int* __restrict__ rs,
        const int* __restrict__ csr, int ndst, unsigned short* __restrict__ agg) {
    int gw   = (blockIdx.x * 256 + threadIdx.x) >> 6;
    int nw   = (gridDim.x * 256) >> 6;
    int lane = threadIdx.x & 63;
    int sub  = lane >> 4;          // 0..3  neighbor stripe
    int sl   = lane & 15;          // 16 lanes x 16B = 256B row
    for (int d = gw; d < ndst; d += nw) {
        int s0 = rs[d], s1 = rs[d + 1];
        float acc[8] = {0.f, 0.f, 0.f, 0.f, 0.f, 0.f, 0.f, 0.f};
        for (int j = s0 + sub; j < s1; j += 4) {
            int s = csr[j];
            uint4 v = *(const uint4*)(xsrc + (size_t)s * D + sl * 8);
            acc[0] += bflo(v.x); acc[1] += bfhi(v.x);
            acc[2] += bflo(v.y); acc[3] += bfhi(v.y);
            acc[4] += bflo(v.z); acc[5] += bfhi(v.z);
            acc[6] += bflo(v.w); acc[7] += bfhi(v.w);
        }
#pragma unroll
        for (int i = 0; i < 8; ++i) {
            acc[i] += __shfl_xor(acc[i], 16);
            acc[i] += __shfl_xor(acc[i], 32);
        }
        if (sub == 0) {
            uint4 o;
            o.x = f2bf(acc[0]) | ((unsigned)f2bf(acc[1]) << 16);
            o.y = f2bf(acc[2]) | ((unsigned)f2bf(acc[3]) << 16);
            o.z = f2bf(acc[4]) | ((unsigned)f2bf(acc[5]) << 16);
            o.w = f2bf(acc[6]) | ((unsigned)f2bf(acc[7]) << 16);
            *(uint4*)(agg + (size_t)d * D + sl * 8) = o;
        }
    }
}

// ---------------------------------------------------------------------------
// MFMA node update (unchanged): out = maybe_relu([xs|xm]@Bpack + bs+deg*bm)
// ---------------------------------------------------------------------------
__global__ __launch_bounds__(256) void linear_mfma_bf16(
        const unsigned short* __restrict__ xs, const unsigned short* __restrict__ xm,
        const unsigned short* __restrict__ Bpack,
        const float* __restrict__ bs, const float* __restrict__ bm,
        const int* __restrict__ deg, int relu, int n,
        unsigned short* __restrict__ out) {
    __shared__ uint4 lds4[2048];   // 32 KB
    unsigned char* lds = (unsigned char*)lds4;
    int tid = threadIdx.x;
    int wave = tid >> 6, lane = tid & 63;
    int r_base = blockIdx.x * 64;

#pragma unroll
    for (int i = 0; i < 8; ++i) {
        int c = i * 256 + tid;        // 0..2047
        int row = c >> 5;             // 0..63
        int kc = (c & 31) * 8;        // bf16 elem offset 0..248
        int rg = r_base + row;
        uint4 w = make_uint4(0, 0, 0, 0);
        if (rg < n) {
            const unsigned short* src = (kc < D) ? (xs + (size_t)rg * D + kc)
                                                 : (xm + (size_t)rg * D + (kc - D));
            w = *(const uint4*)src;
        }
        unsigned addr = ((unsigned)(row * 512 + kc * 2)) ^ ((unsigned)((row & 7) << 4));
        *(uint4*)(lds + addr) = w;
    }
    __syncthreads();

    int lrow = wave * 16 + (lane & 15);
    bf16x8_t a[8];
#pragma unroll
    for (int ks = 0; ks < 8; ++ks) {
        unsigned addr = ((unsigned)(lrow * 512 + ks * 64 + (lane >> 4) * 16))
                        ^ ((unsigned)((lrow & 7) << 4));
        a[ks] = *(const bf16x8_t*)(lds + addr);
    }

    f32x4_t acc[8];
#pragma unroll
    for (int nf = 0; nf < 8; ++nf) acc[nf] = (f32x4_t){0.f, 0.f, 0.f, 0.f};

    const bf16x8_t* bp = (const bf16x8_t*)Bpack;
#pragma unroll
    for (int nf = 0; nf < 8; ++nf) {
#pragma unroll
        for (int ks = 0; ks < 8; ++ks) {
            bf16x8_t b = bp[(nf * 8 + ks) * 64 + lane];
            acc[nf] = __builtin_amdgcn_mfma_f32_16x16x32_bf16(a[ks], b, acc[nf], 0, 0, 0);
        }
    }

    int rb2 = r_base + wave * 16 + (lane >> 4) * 4;
    float dg[4];
#pragma unroll
    for (int rr = 0; rr < 4; ++rr)
        dg[rr] = (rb2 + rr < n) ? (float)deg[rb2 + rr] : 0.f;

#pragma unroll
    for (int nf = 0; nf < 8; ++nf) {
        int col = nf * 16 + (lane & 15);
        float bsv = bs[col], bmv = bm[col];
#pragma unroll
        for (int rr = 0; rr < 4; ++rr) {
            int r = rb2 + rr;
            if (r < n) {
                float v = acc[nf][rr] + bsv + dg[rr] * bmv;
                if (relu) v = fmaxf(v, 0.f);
                out[(size_t)r * D + col] = f2bf(v);
            }
        }
    }
}

// ---------------------------------------------------------------------------
// supervision dot products on bf16 embeddings: one wave per pair
// ---------------------------------------------------------------------------
__global__ __launch_bounds__(256) void dot_kernel(
        const unsigned short* __restrict__ za, const unsigned short* __restrict__ zp,
        const int* __restrict__ sa, const int* __restrict__ sp, int S,
        float* __restrict__ out) {
    int gw   = (blockIdx.x * 256 + threadIdx.x) >> 6;
    int lane = threadIdx.x & 63;
    int nw   = (gridDim.x * 256) >> 6;
    for (int i = gw; i < S; i += nw) {
        int a = sa[i], p = sp[i];
        unsigned ua = *(const unsigned*)(za + (size_t)a * D + lane * 2);
        unsigned up = *(const unsigned*)(zp + (size_t)p * D + lane * 2);
        float s = bflo(ua) * bflo(up) + bfhi(ua) * bfhi(up);
#pragma unroll
        for (int off = 32; off > 0; off >>= 1) s += __shfl_xor(s, off);
        if (lane == 0) out[i] = s;
    }
}

// ---------------------------------------------------------------------------
extern "C" void kernel_launch(void* const* d_in, const int* in_sizes, int n_in,
                              void* d_out, int out_size, void* d_ws, size_t ws_size,
                              hipStream_t stream) {
    const float* x_a  = (const float*)d_in[0];
    const float* x_p  = (const float*)d_in[1];
    const int*   ea   = (const int*)d_in[2];
    const int*   ep   = (const int*)d_in[3];
    const int*   sa   = (const int*)d_in[4];
    const int*   sp   = (const int*)d_in[5];
    const float* WsA  = (const float*)d_in[6];
    const float* bsA  = (const float*)d_in[7];
    const float* WsP  = (const float*)d_in[8];
    const float* bsP  = (const float*)d_in[9];
    const float* Wa2p = (const float*)d_in[10];
    const float* ba2p = (const float*)d_in[11];
    const float* Wp2a = (const float*)d_in[12];
    const float* bp2a = (const float*)d_in[13];

    const int nA = in_sizes[0] / D;   // 100000
    const int nP = in_sizes[1] / D;   // 200000
    const int E  = in_sizes[2];       // 600000
    const int S  = in_sizes[4];       // 100000

    // ---- workspace layout ----
    char* ws = (char*)d_ws;
    size_t curoff = 0;
    auto alloc = [&](size_t bytes) -> void* {
        void* p = ws + curoff;
        curoff = (curoff + bytes + 255) & ~(size_t)255;
        return p;
    };
    unsigned short* xb_a  = (unsigned short*)alloc((size_t)nA * D * 2);
    unsigned short* xb_p  = (unsigned short*)alloc((size_t)nP * D * 2);
    unsigned short* agg_a = (unsigned short*)alloc((size_t)nA * D * 2);
    unsigned short* agg_p = (unsigned short*)alloc((size_t)nP * D * 2);
    unsigned short* y_a   = (unsigned short*)alloc((size_t)nA * D * 2);
    unsigned short* y_p   = (unsigned short*)alloc((size_t)nP * D * 2);
    unsigned short* z_a   = (unsigned short*)alloc((size_t)nA * D * 2);
    unsigned short* z_p   = (unsigned short*)alloc((size_t)nP * D * 2);
    int* degA = (int*)alloc((size_t)nA * 4);
    int* degP = (int*)alloc((size_t)nP * 4);
    int* rsA  = (int*)alloc(((size_t)nA + 1) * 4);
    int* rsP  = (int*)alloc(((size_t)nP + 1) * 4);
    int* csrA = (int*)alloc((size_t)E * 4);
    int* csrP = (int*)alloc((size_t)E * 4);
    const int gA = (nA + SCAN_TILE - 1) / SCAN_TILE;
    const int gP = (nP + SCAN_TILE - 1) / SCAN_TILE;
    int* partials = (int*)alloc((size_t)(gA + gP) * 4);
    unsigned short* Bpack = (unsigned short*)alloc((size_t)4 * 32768 * 2);  // 256 KB

    // bucket structures alias z_a/z_p (preprocessing finishes before layer 1)
    const int nbA = (nA + 63) >> 6;   // 1563
    const int nbP = (nP + 63) >> 6;   // 3125
    unsigned* bufA = (unsigned*)z_a;          // E*4 = 2.4 MB  (z_a is 25.6 MB)
    unsigned* bufP = bufA + E;                // E*4
    int* bcurA = (int*)z_p;                   // tiny
    int* bcurP = bcurA + nbA;

    // ---- bf16 input copies + graph preprocessing + W packing ----
    f32_to_bf16_kernel<<<1024, 256, 0, stream>>>(x_a, xb_a, nA * D / 8);
    f32_to_bf16_kernel<<<2048, 256, 0, stream>>>(x_p, xb_p, nP * D / 8);
    size_t deg_bytes = (size_t)((char*)degP - (char*)degA) + (size_t)nP * 4;
    hipMemsetAsync(degA, 0, deg_bytes, stream);
    pack_w_kernel<<<64, 256, 0, stream>>>(WsA, WsP, Wa2p, Wp2a, Bpack);
    count_deg_kernel<<<1024, 256, 0, stream>>>(ea, ep, E, degA, degP);
    scan_partials_kernel<<<gA + gP, 256, 0, stream>>>(degA, nA, degP, nP, gA, partials);
    scan_block_sums_kernel<<<1, 1024, 0, stream>>>(partials, gA, gP, rsA + nA, rsP + nP);
    scan_write_kernel<<<gA + gP, 256, 0, stream>>>(degA, nA, rsA,
                                                   degP, nP, rsP, gA, partials);
    bcur_init_kernel<<<(nbA + nbP + 255) / 256, 256, 0, stream>>>(
        rsA, nbA, bcurA, rsP, nbP, bcurP);
    bucket_scatter_kernel<<<1024, 256, 0, stream>>>(ea, ep, E, bcurA, bcurP, bufA, bufP);
    bucket_to_csr_kernel<<<nbA + nbP, 256, 0, stream>>>(
        rsA, bufA, nA, nbA, csrA, rsP, bufP, nP, nbP, csrP);

    const int gmA = (nA + 63) / 64;   // 1563
    const int gmP = (nP + 63) / 64;   // 3125

    // ---- layer 0 (relu) ----
    aggregate_bf16_kernel<<<(nA + 3) / 4, 256, 0, stream>>>(xb_p, rsA, csrA, nA, agg_a);
    aggregate_bf16_kernel<<<(nP + 3) / 4, 256, 0, stream>>>(xb_a, rsP, csrP, nP, agg_p);
    linear_mfma_bf16<<<gmA, 256, 0, stream>>>(xb_a, agg_a, Bpack + 0 * 32768,
                                              bsA, bp2a, degA, 1, nA, y_a);
    linear_mfma_bf16<<<gmP, 256, 0, stream>>>(xb_p, agg_p, Bpack + 1 * 32768,
                                              bsP, ba2p, degP, 1, nP, y_p);

    // ---- layer 1 (no relu) ----
    aggregate_bf16_kernel<<<(nA + 3) / 4, 256, 0, stream>>>(y_p, rsA, csrA, nA, agg_a);
    aggregate_bf16_kernel<<<(nP + 3) / 4, 256, 0, stream>>>(y_a, rsP, csrP, nP, agg_p);
    linear_mfma_bf16<<<gmA, 256, 0, stream>>>(y_a, agg_a, Bpack + 2 * 32768,
                                              bsA + D, bp2a + D, degA, 0, nA, z_a);
    linear_mfma_bf16<<<gmP, 256, 0, stream>>>(y_p, agg_p, Bpack + 3 * 32768,
                                              bsP + D, ba2p + D, degP, 0, nP, z_p);

    // ---- supervision scores ----
    dot_kernel<<<(S + 3) / 4, 256, 0, stream>>>(z_a, z_p, sa, sp, S, (float*)d_out);
}

// Round 7
// 549.135 us; speedup vs baseline: 1.1466x; 1.1466x over previous
//
#include <hip/hip_runtime.h>
#include <stdint.h>

#define D 128
#define SCAN_TILE 1024  // elements per scan block (256 thr x 4)
#define CB_SHIFT 11     // coarse bucket = 2048 dst nodes
#define CB_NODES 2048
#define CHE 2048        // edges per multisplit chunk (2*CHE entries)

typedef __attribute__((ext_vector_type(8))) short bf16x8_t;
typedef __attribute__((ext_vector_type(4))) float f32x4_t;

__device__ inline unsigned short f2bf(float x) {
    unsigned int u = __float_as_uint(x);
    unsigned int r = (u + 0x7fffu + ((u >> 16) & 1u)) >> 16;   // RNE
    return (unsigned short)r;
}
__device__ inline float bflo(unsigned v) { return __uint_as_float(v << 16); }
__device__ inline float bfhi(unsigned v) { return __uint_as_float(v & 0xffff0000u); }

// ---------------------------------------------------------------------------
// f32 -> bf16 bulk convert
// ---------------------------------------------------------------------------
__global__ __launch_bounds__(256) void f32_to_bf16_kernel(
        const float* __restrict__ in, unsigned short* __restrict__ out, int n8) {
    int stride = gridDim.x * blockDim.x;
    for (int i = blockIdx.x * blockDim.x + threadIdx.x; i < n8; i += stride) {
        float4 v0 = *(const float4*)(in + (size_t)i * 8);
        float4 v1 = *(const float4*)(in + (size_t)i * 8 + 4);
        uint4 o;
        o.x = f2bf(v0.x) | ((unsigned)f2bf(v0.y) << 16);
        o.y = f2bf(v0.z) | ((unsigned)f2bf(v0.w) << 16);
        o.z = f2bf(v1.x) | ((unsigned)f2bf(v1.y) << 16);
        o.w = f2bf(v1.z) | ((unsigned)f2bf(v1.w) << 16);
        *(uint4*)(out + (size_t)i * 8) = o;
    }
}

// ---------------------------------------------------------------------------
// deg histogram
// ---------------------------------------------------------------------------
__global__ void count_deg_kernel(const int* __restrict__ ea, const int* __restrict__ ep,
                                 int E, int* __restrict__ degA, int* __restrict__ degP) {
    int stride = gridDim.x * blockDim.x;
    for (int e = blockIdx.x * blockDim.x + threadIdx.x; e < E; e += stride) {
        atomicAdd(&degA[ea[e]], 1);
        atomicAdd(&degP[ep[e]], 1);
    }
}

// ---------------------------------------------------------------------------
// 3-pass device-wide exclusive scan over BOTH deg arrays
// ---------------------------------------------------------------------------
__global__ __launch_bounds__(256) void scan_partials_kernel(
        const int* __restrict__ degA, int nA,
        const int* __restrict__ degP, int nP, int gA,
        int* __restrict__ partials) {
    const int* deg; int n;
    int b = blockIdx.x;
    if (b < gA) { deg = degA; n = nA; }
    else        { deg = degP; n = nP; b -= gA; }
    int tid = threadIdx.x;
    int i0 = b * SCAN_TILE + tid * 4;
    int s = 0;
    if (i0 + 3 < n) {
        int4 d = *(const int4*)(deg + i0);
        s = d.x + d.y + d.z + d.w;
    } else {
        for (int j = 0; j < 4; ++j) if (i0 + j < n) s += deg[i0 + j];
    }
#pragma unroll
    for (int off = 32; off; off >>= 1) s += __shfl_xor(s, off);
    __shared__ int wsum[4];
    if ((tid & 63) == 0) wsum[tid >> 6] = s;
    __syncthreads();
    if (tid == 0) partials[blockIdx.x] = wsum[0] + wsum[1] + wsum[2] + wsum[3];
}

__global__ __launch_bounds__(1024) void scan_block_sums_kernel(
        int* __restrict__ partials, int gA, int gP,
        int* __restrict__ rsA_end, int* __restrict__ rsP_end) {
    __shared__ int s[1024];
    int n = gA + gP;
    int tid = threadIdx.x;
    int v = (tid < n) ? partials[tid] : 0;
    s[tid] = v;
    __syncthreads();
    for (int off = 1; off < 1024; off <<= 1) {
        int add = 0;
        if (tid >= off && ((tid < gA) || (tid - off >= gA))) add = s[tid - off];
        __syncthreads();
        s[tid] += add;
        __syncthreads();
    }
    if (tid == gA - 1)  *rsA_end = s[tid];
    if (tid == n - 1)   *rsP_end = s[tid];
    if (tid < n) partials[tid] = s[tid] - v;
}

__global__ __launch_bounds__(256) void scan_write_kernel(
        const int* __restrict__ degA, int nA, int* __restrict__ rsA,
        const int* __restrict__ degP, int nP, int* __restrict__ rsP,
        int gA, const int* __restrict__ partials) {
    const int* deg; int n; int* rs;
    int b = blockIdx.x;
    int part = partials[blockIdx.x];
    if (b < gA) { deg = degA; n = nA; rs = rsA; }
    else        { deg = degP; n = nP; rs = rsP; b -= gA; }
    int tid = threadIdx.x;
    int lane = tid & 63, wid = tid >> 6;
    int i0 = b * SCAN_TILE + tid * 4;

    int4 d = make_int4(0, 0, 0, 0);
    if (i0 + 3 < n) {
        d = *(const int4*)(deg + i0);
    } else {
        if (i0 + 0 < n) d.x = deg[i0 + 0];
        if (i0 + 1 < n) d.y = deg[i0 + 1];
        if (i0 + 2 < n) d.z = deg[i0 + 2];
        if (i0 + 3 < n) d.w = deg[i0 + 3];
    }
    int tsum = d.x + d.y + d.z + d.w;

    int x = tsum;
#pragma unroll
    for (int off = 1; off < 64; off <<= 1) {
        int y = __shfl_up(x, off);
        if (lane >= off) x += y;
    }
    int excl = x - tsum;

    __shared__ int wsum[4];
    if (lane == 63) wsum[wid] = x;
    __syncthreads();
    int woff = 0;
#pragma unroll
    for (int w = 0; w < 4; ++w) if (w < wid) woff += wsum[w];

    int off0 = part + woff + excl;
    int4 o;
    o.x = off0;
    o.y = off0 + d.x;
    o.z = o.y + d.y;
    o.w = o.z + d.z;
    if (i0 + 3 < n) {
        *(int4*)(rs + i0) = o;
    } else {
        if (i0 + 0 < n) rs[i0 + 0] = o.x;
        if (i0 + 1 < n) rs[i0 + 1] = o.y;
        if (i0 + 2 < n) rs[i0 + 2] = o.z;
        if (i0 + 3 < n) rs[i0 + 3] = o.w;
    }
}

// ---------------------------------------------------------------------------
// coarse cursor init: gcur[b] = start of coarse bucket b's region in buf.
// A buckets [0,nbcA) -> buf[0..E); P buckets [nbcA,NBC) -> buf[E..2E).
// ---------------------------------------------------------------------------
__global__ __launch_bounds__(256) void gcur_init_kernel(
        const int* __restrict__ rsA, int nbcA,
        const int* __restrict__ rsP, int nbc, int E, int* __restrict__ gcur) {
    int i = blockIdx.x * blockDim.x + threadIdx.x;
    if (i < nbcA)                gcur[i] = rsA[i << CB_SHIFT];
    else if (i < nbc)            gcur[i] = E + rsP[(i - nbcA) << CB_SHIFT];
}

// ---------------------------------------------------------------------------
// LDS multisplit: chunk of CHE edges -> 2*CHE entries grouped by coarse
// bucket, written as BLOCK-OWNED contiguous runs (one global atomicAdd per
// (block,bucket) claims the run). This keeps each 64B line's writes on one
// CU/XCD -> no partial-line writeback amplification (round-6 lesson).
// Entry = (src<<11) | (dst & 2047); src < 2^18 -> fits 29 bits.
// ---------------------------------------------------------------------------
__global__ __launch_bounds__(256) void multisplit_kernel(
        const int* __restrict__ ea, const int* __restrict__ ep, int E,
        int nbcA, int* __restrict__ gcur, unsigned* __restrict__ buf) {
    __shared__ int hist[256];
    __shared__ int off[256];
    __shared__ int cnt2[256];
    __shared__ int gbase[256];
    __shared__ unsigned cbuf[2 * CHE];
    __shared__ unsigned char bkt[2 * CHE];

    int tid = threadIdx.x;
    int e0 = blockIdx.x * CHE;
    int ecnt = E - e0; if (ecnt > CHE) ecnt = CHE;

    hist[tid] = 0;
    __syncthreads();

    // pass 1: count
    for (int k = tid; k < ecnt; k += 256) {
        int a = ea[e0 + k], p = ep[e0 + k];
        atomicAdd(&hist[a >> CB_SHIFT], 1);
        atomicAdd(&hist[nbcA + (p >> CB_SHIFT)], 1);
    }
    __syncthreads();

    // exclusive scan (Hillis-Steele over 256)
    int v = hist[tid];
    off[tid] = v;
    __syncthreads();
    for (int o = 1; o < 256; o <<= 1) {
        int y = (tid >= o) ? off[tid - o] : 0;
        __syncthreads();
        off[tid] += y;
        __syncthreads();
    }
    int excl = off[tid] - v;
    off[tid] = excl;
    cnt2[tid] = 0;
    if (v > 0) gbase[tid] = atomicAdd(&gcur[tid], v);
    __syncthreads();

    // pass 2: place into LDS compact buffer
    for (int k = tid; k < ecnt; k += 256) {
        int a = ea[e0 + k], p = ep[e0 + k];
        int bA = a >> CB_SHIFT;
        int iA = off[bA] + atomicAdd(&cnt2[bA], 1);
        cbuf[iA] = ((unsigned)p << CB_SHIFT) | (unsigned)(a & (CB_NODES - 1));
        bkt[iA] = (unsigned char)bA;
        int bP = nbcA + (p >> CB_SHIFT);
        int iP = off[bP] + atomicAdd(&cnt2[bP], 1);
        cbuf[iP] = ((unsigned)a << CB_SHIFT) | (unsigned)(p & (CB_NODES - 1));
        bkt[iP] = (unsigned char)bP;
    }
    __syncthreads();

    // write out: per-bucket contiguous runs
    int total = 2 * ecnt;
    for (int i = tid; i < total; i += 256) {
        int b = bkt[i];
        buf[(size_t)gbase[b] + (i - off[b])] = cbuf[i];
    }
}

// ---------------------------------------------------------------------------
// fine sort: one block per coarse bucket; scatter src into the bucket's
// contiguous csr region via LDS per-dst cursors (region is L2-resident on
// one XCD -> dense eviction).
// ---------------------------------------------------------------------------
__global__ __launch_bounds__(1024) void fine_csr_kernel(
        const int* __restrict__ rsA, int nA, int nbcA, int* __restrict__ csrA,
        const int* __restrict__ rsP, int nP, int* __restrict__ csrP,
        const unsigned* __restrict__ buf, int E) {
    __shared__ int base[CB_NODES + 1];
    __shared__ int cnt[CB_NODES];
    const int* rs; int* csr; int n; int d0; const unsigned* mybuf;
    int b = blockIdx.x;
    if (b < nbcA) { rs = rsA; csr = csrA; n = nA; d0 = b << CB_SHIFT; mybuf = buf; }
    else { rs = rsP; csr = csrP; n = nP; d0 = (b - nbcA) << CB_SHIFT; mybuf = buf + E; }
    int nd = n - d0; if (nd > CB_NODES) nd = CB_NODES;

    int tid = threadIdx.x;
    for (int i = tid; i <= nd; i += 1024) base[i] = rs[d0 + i];
    for (int i = tid; i < nd; i += 1024) cnt[i] = 0;
    __syncthreads();

    int g0 = base[0], g1 = base[nd];
    for (int j = g0 + tid; j < g1; j += 1024) {
        unsigned pk = mybuf[j];
        int li = pk & (CB_NODES - 1);
        int src = (int)(pk >> CB_SHIFT);
        int pos = base[li] + atomicAdd(&cnt[li], 1);
        csr[pos] = src;
    }
}

// ---------------------------------------------------------------------------
// W pre-pack (unchanged): Bcat=[Ws;Wm] -> bf16 MFMA fragment order
// ---------------------------------------------------------------------------
__global__ __launch_bounds__(256) void pack_w_kernel(
        const float* __restrict__ WsA, const float* __restrict__ WsP,
        const float* __restrict__ Wa2p, const float* __restrict__ Wp2a,
        unsigned short* __restrict__ Bpack) {
    int combo = blockIdx.x >> 4;
    int e = (blockIdx.x & 15) * 256 + threadIdx.x;   // 0..4095
    int layer = combo >> 1;
    const float* Ws = ((combo & 1) ? WsP : WsA) + (size_t)layer * D * D;
    const float* Wm = ((combo & 1) ? Wa2p : Wp2a) + (size_t)layer * D * D;

    int f = e >> 6, lane = e & 63;
    int nf = f >> 3, ks = f & 7;
    int k0 = ks * 32 + (lane >> 4) * 8;
    int col = nf * 16 + (lane & 15);

    unsigned short v[8];
#pragma unroll
    for (int j = 0; j < 8; ++j) {
        int k = k0 + j;
        float x = (k < D) ? Ws[(size_t)k * D + col] : Wm[(size_t)(k - D) * D + col];
        v[j] = f2bf(x);
    }
    uint4 o;
    o.x = v[0] | ((unsigned)v[1] << 16);
    o.y = v[2] | ((unsigned)v[3] << 16);
    o.z = v[4] | ((unsigned)v[5] << 16);
    o.w = v[6] | ((unsigned)v[7] << 16);
    *(uint4*)(Bpack + (size_t)combo * 32768 + (size_t)e * 8) = o;
}

// ---------------------------------------------------------------------------
// bf16 pull-aggregation (unchanged): one wave per dst row, 4x16-lane subwaves
// ---------------------------------------------------------------------------
__global__ __launch_bounds__(256) void aggregate_bf16_kernel(
        const unsigned short* __restrict__ xsrc, const int* __restrict__ rs,
        const int* __restrict__ csr, int ndst, unsigned short* __restrict__ agg) {
    int gw   = (blockIdx.x * 256 + threadIdx.x) >> 6;
    int nw   = (gridDim.x * 256) >> 6;
    int lane = threadIdx.x & 63;
    int sub  = lane >> 4;          // 0..3  neighbor stripe
    int sl   = lane & 15;          // 16 lanes x 16B = 256B row
    for (int d = gw; d < ndst; d += nw) {
        int s0 = rs[d], s1 = rs[d + 1];
        float acc[8] = {0.f, 0.f, 0.f, 0.f, 0.f, 0.f, 0.f, 0.f};
        for (int j = s0 + sub; j < s1; j += 4) {
            int s = csr[j];
            uint4 v = *(const uint4*)(xsrc + (size_t)s * D + sl * 8);
            acc[0] += bflo(v.x); acc[1] += bfhi(v.x);
            acc[2] += bflo(v.y); acc[3] += bfhi(v.y);
            acc[4] += bflo(v.z); acc[5] += bfhi(v.z);
            acc[6] += bflo(v.w); acc[7] += bfhi(v.w);
        }
#pragma unroll
        for (int i = 0; i < 8; ++i) {
            acc[i] += __shfl_xor(acc[i], 16);
            acc[i] += __shfl_xor(acc[i], 32);
        }
        if (sub == 0) {
            uint4 o;
            o.x = f2bf(acc[0]) | ((unsigned)f2bf(acc[1]) << 16);
            o.y = f2bf(acc[2]) | ((unsigned)f2bf(acc[3]) << 16);
            o.z = f2bf(acc[4]) | ((unsigned)f2bf(acc[5]) << 16);
            o.w = f2bf(acc[6]) | ((unsigned)f2bf(acc[7]) << 16);
            *(uint4*)(agg + (size_t)d * D + sl * 8) = o;
        }
    }
}

// ---------------------------------------------------------------------------
// MFMA node update (unchanged): out = maybe_relu([xs|xm]@Bpack + bs+deg*bm)
// ---------------------------------------------------------------------------
__global__ __launch_bounds__(256) void linear_mfma_bf16(
        const unsigned short* __restrict__ xs, const unsigned short* __restrict__ xm,
        const unsigned short* __restrict__ Bpack,
        const float* __restrict__ bs, const float* __restrict__ bm,
        const int* __restrict__ deg, int relu, int n,
        unsigned short* __restrict__ out) {
    __shared__ uint4 lds4[2048];   // 32 KB
    unsigned char* lds = (unsigned char*)lds4;
    int tid = threadIdx.x;
    int wave = tid >> 6, lane = tid & 63;
    int r_base = blockIdx.x * 64;

#pragma unroll
    for (int i = 0; i < 8; ++i) {
        int c = i * 256 + tid;        // 0..2047
        int row = c >> 5;             // 0..63
        int kc = (c & 31) * 8;        // bf16 elem offset 0..248
        int rg = r_base + row;
        uint4 w = make_uint4(0, 0, 0, 0);
        if (rg < n) {
            const unsigned short* src = (kc < D) ? (xs + (size_t)rg * D + kc)
                                                 : (xm + (size_t)rg * D + (kc - D));
            w = *(const uint4*)src;
        }
        unsigned addr = ((unsigned)(row * 512 + kc * 2)) ^ ((unsigned)((row & 7) << 4));
        *(uint4*)(lds + addr) = w;
    }
    __syncthreads();

    int lrow = wave * 16 + (lane & 15);
    bf16x8_t a[8];
#pragma unroll
    for (int ks = 0; ks < 8; ++ks) {
        unsigned addr = ((unsigned)(lrow * 512 + ks * 64 + (lane >> 4) * 16))
                        ^ ((unsigned)((lrow & 7) << 4));
        a[ks] = *(const bf16x8_t*)(lds + addr);
    }

    f32x4_t acc[8];
#pragma unroll
    for (int nf = 0; nf < 8; ++nf) acc[nf] = (f32x4_t){0.f, 0.f, 0.f, 0.f};

    const bf16x8_t* bp = (const bf16x8_t*)Bpack;
#pragma unroll
    for (int nf = 0; nf < 8; ++nf) {
#pragma unroll
        for (int ks = 0; ks < 8; ++ks) {
            bf16x8_t b = bp[(nf * 8 + ks) * 64 + lane];
            acc[nf] = __builtin_amdgcn_mfma_f32_16x16x32_bf16(a[ks], b, acc[nf], 0, 0, 0);
        }
    }

    int rb2 = r_base + wave * 16 + (lane >> 4) * 4;
    float dg[4];
#pragma unroll
    for (int rr = 0; rr < 4; ++rr)
        dg[rr] = (rb2 + rr < n) ? (float)deg[rb2 + rr] : 0.f;

#pragma unroll
    for (int nf = 0; nf < 8; ++nf) {
        int col = nf * 16 + (lane & 15);
        float bsv = bs[col], bmv = bm[col];
#pragma unroll
        for (int rr = 0; rr < 4; ++rr) {
            int r = rb2 + rr;
            if (r < n) {
                float v = acc[nf][rr] + bsv + dg[rr] * bmv;
                if (relu) v = fmaxf(v, 0.f);
                out[(size_t)r * D + col] = f2bf(v);
            }
        }
    }
}

// ---------------------------------------------------------------------------
// supervision dot products on bf16 embeddings: one wave per pair
// ---------------------------------------------------------------------------
__global__ __launch_bounds__(256) void dot_kernel(
        const unsigned short* __restrict__ za, const unsigned short* __restrict__ zp,
        const int* __restrict__ sa, const int* __restrict__ sp, int S,
        float* __restrict__ out) {
    int gw   = (blockIdx.x * 256 + threadIdx.x) >> 6;
    int lane = threadIdx.x & 63;
    int nw   = (gridDim.x * 256) >> 6;
    for (int i = gw; i < S; i += nw) {
        int a = sa[i], p = sp[i];
        unsigned ua = *(const unsigned*)(za + (size_t)a * D + lane * 2);
        unsigned up = *(const unsigned*)(zp + (size_t)p * D + lane * 2);
        float s = bflo(ua) * bflo(up) + bfhi(ua) * bfhi(up);
#pragma unroll
        for (int off = 32; off > 0; off >>= 1) s += __shfl_xor(s, off);
        if (lane == 0) out[i] = s;
    }
}

// ---------------------------------------------------------------------------
extern "C" void kernel_launch(void* const* d_in, const int* in_sizes, int n_in,
                              void* d_out, int out_size, void* d_ws, size_t ws_size,
                              hipStream_t stream) {
    const float* x_a  = (const float*)d_in[0];
    const float* x_p  = (const float*)d_in[1];
    const int*   ea   = (const int*)d_in[2];
    const int*   ep   = (const int*)d_in[3];
    const int*   sa   = (const int*)d_in[4];
    const int*   sp   = (const int*)d_in[5];
    const float* WsA  = (const float*)d_in[6];
    const float* bsA  = (const float*)d_in[7];
    const float* WsP  = (const float*)d_in[8];
    const float* bsP  = (const float*)d_in[9];
    const float* Wa2p = (const float*)d_in[10];
    const float* ba2p = (const float*)d_in[11];
    const float* Wp2a = (const float*)d_in[12];
    const float* bp2a = (const float*)d_in[13];

    const int nA = in_sizes[0] / D;   // 100000
    const int nP = in_sizes[1] / D;   // 200000
    const int E  = in_sizes[2];       // 600000
    const int S  = in_sizes[4];       // 100000

    // ---- workspace layout ----
    char* ws = (char*)d_ws;
    size_t curoff = 0;
    auto alloc = [&](size_t bytes) -> void* {
        void* p = ws + curoff;
        curoff = (curoff + bytes + 255) & ~(size_t)255;
        return p;
    };
    unsigned short* xb_a  = (unsigned short*)alloc((size_t)nA * D * 2);
    unsigned short* xb_p  = (unsigned short*)alloc((size_t)nP * D * 2);
    unsigned short* agg_a = (unsigned short*)alloc((size_t)nA * D * 2);
    unsigned short* agg_p = (unsigned short*)alloc((size_t)nP * D * 2);
    unsigned short* y_a   = (unsigned short*)alloc((size_t)nA * D * 2);
    unsigned short* y_p   = (unsigned short*)alloc((size_t)nP * D * 2);
    unsigned short* z_a   = (unsigned short*)alloc((size_t)nA * D * 2);
    unsigned short* z_p   = (unsigned short*)alloc((size_t)nP * D * 2);
    int* degA = (int*)alloc((size_t)nA * 4);
    int* degP = (int*)alloc((size_t)nP * 4);
    int* rsA  = (int*)alloc(((size_t)nA + 1) * 4);
    int* rsP  = (int*)alloc(((size_t)nP + 1) * 4);
    int* csrA = (int*)alloc((size_t)E * 4);
    int* csrP = (int*)alloc((size_t)E * 4);
    const int gA = (nA + SCAN_TILE - 1) / SCAN_TILE;
    const int gP = (nP + SCAN_TILE - 1) / SCAN_TILE;
    int* partials = (int*)alloc((size_t)(gA + gP) * 4);
    unsigned short* Bpack = (unsigned short*)alloc((size_t)4 * 32768 * 2);  // 256 KB

    // multisplit structures alias z_a/z_p (preprocessing ends before layer 1)
    const int nbcA = (nA + CB_NODES - 1) >> CB_SHIFT;   // 49
    const int nbcP = (nP + CB_NODES - 1) >> CB_SHIFT;   // 98
    const int NBC  = nbcA + nbcP;                       // 147
    unsigned* buf = (unsigned*)z_a;           // 2E*4 = 4.8 MB (z_a is 25.6 MB)
    int* gcur = (int*)z_p;                    // NBC ints

    // ---- bf16 input copies + graph preprocessing + W packing ----
    f32_to_bf16_kernel<<<1024, 256, 0, stream>>>(x_a, xb_a, nA * D / 8);
    f32_to_bf16_kernel<<<2048, 256, 0, stream>>>(x_p, xb_p, nP * D / 8);
    size_t deg_bytes = (size_t)((char*)degP - (char*)degA) + (size_t)nP * 4;
    hipMemsetAsync(degA, 0, deg_bytes, stream);
    pack_w_kernel<<<64, 256, 0, stream>>>(WsA, WsP, Wa2p, Wp2a, Bpack);
    count_deg_kernel<<<1024, 256, 0, stream>>>(ea, ep, E, degA, degP);
    scan_partials_kernel<<<gA + gP, 256, 0, stream>>>(degA, nA, degP, nP, gA, partials);
    scan_block_sums_kernel<<<1, 1024, 0, stream>>>(partials, gA, gP, rsA + nA, rsP + nP);
    scan_write_kernel<<<gA + gP, 256, 0, stream>>>(degA, nA, rsA,
                                                   degP, nP, rsP, gA, partials);
    gcur_init_kernel<<<1, 256, 0, stream>>>(rsA, nbcA, rsP, NBC, E, gcur);
    multisplit_kernel<<<(E + CHE - 1) / CHE, 256, 0, stream>>>(ea, ep, E, nbcA, gcur, buf);
    fine_csr_kernel<<<NBC, 1024, 0, stream>>>(rsA, nA, nbcA, csrA,
                                              rsP, nP, csrP, buf, E);

    const int gmA = (nA + 63) / 64;   // 1563
    const int gmP = (nP + 63) / 64;   // 3125

    // ---- layer 0 (relu) ----
    aggregate_bf16_kernel<<<(nA + 3) / 4, 256, 0, stream>>>(xb_p, rsA, csrA, nA, agg_a);
    aggregate_bf16_kernel<<<(nP + 3) / 4, 256, 0, stream>>>(xb_a, rsP, csrP, nP, agg_p);
    linear_mfma_bf16<<<gmA, 256, 0, stream>>>(xb_a, agg_a, Bpack + 0 * 32768,
                                              bsA, bp2a, degA, 1, nA, y_a);
    linear_mfma_bf16<<<gmP, 256, 0, stream>>>(xb_p, agg_p, Bpack + 1 * 32768,
                                              bsP, ba2p, degP, 1, nP, y_p);

    // ---- layer 1 (no relu) ----
    aggregate_bf16_kernel<<<(nA + 3) / 4, 256, 0, stream>>>(y_p, rsA, csrA, nA, agg_a);
    aggregate_bf16_kernel<<<(nP + 3) / 4, 256, 0, stream>>>(y_a, rsP, csrP, nP, agg_p);
    linear_mfma_bf16<<<gmA, 256, 0, stream>>>(y_a, agg_a, Bpack + 2 * 32768,
                                              bsA + D, bp2a + D, degA, 0, nA, z_a);
    linear_mfma_bf16<<<gmP, 256, 0, stream>>>(y_p, agg_p, Bpack + 3 * 32768,
                                              bsP + D, ba2p + D, degP, 0, nP, z_p);

    // ---- supervision scores ----
    dot_kernel<<<(S + 3) / 4, 256, 0, stream>>>(z_a, z_p, sa, sp, S, (float*)d_out);
}

// Round 8
// 517.595 us; speedup vs baseline: 1.2165x; 1.0609x over previous
//
#include <hip/hip_runtime.h>
#include <stdint.h>

#define D 128
#define SCAN_TILE 1024  // elements per scan block (256 thr x 4)
#define CB_SHIFT 11     // coarse bucket = 2048 dst nodes
#define CB_NODES 2048
#define CHE 2048        // edges per multisplit chunk (2*CHE entries)

typedef __attribute__((ext_vector_type(8))) short bf16x8_t;
typedef __attribute__((ext_vector_type(4))) float f32x4_t;

__device__ inline unsigned short f2bf(float x) {
    unsigned int u = __float_as_uint(x);
    unsigned int r = (u + 0x7fffu + ((u >> 16) & 1u)) >> 16;   // RNE
    return (unsigned short)r;
}
__device__ inline float bflo(unsigned v) { return __uint_as_float(v << 16); }
__device__ inline float bfhi(unsigned v) { return __uint_as_float(v & 0xffff0000u); }

// ---------------------------------------------------------------------------
// f32 -> bf16 bulk convert, both arrays in one launch
// ---------------------------------------------------------------------------
__global__ __launch_bounds__(256) void f32_to_bf16_duo(
        const float* __restrict__ inA, unsigned short* __restrict__ outA, int n8A,
        const float* __restrict__ inP, unsigned short* __restrict__ outP, int n8P) {
    int stride = gridDim.x * blockDim.x;
    int total = n8A + n8P;
    for (int i = blockIdx.x * blockDim.x + threadIdx.x; i < total; i += stride) {
        const float* in; unsigned short* out; int j;
        if (i < n8A) { in = inA; out = outA; j = i; }
        else         { in = inP; out = outP; j = i - n8A; }
        float4 v0 = *(const float4*)(in + (size_t)j * 8);
        float4 v1 = *(const float4*)(in + (size_t)j * 8 + 4);
        uint4 o;
        o.x = f2bf(v0.x) | ((unsigned)f2bf(v0.y) << 16);
        o.y = f2bf(v0.z) | ((unsigned)f2bf(v0.w) << 16);
        o.z = f2bf(v1.x) | ((unsigned)f2bf(v1.y) << 16);
        o.w = f2bf(v1.z) | ((unsigned)f2bf(v1.w) << 16);
        *(uint4*)(out + (size_t)j * 8) = o;
    }
}

// ---------------------------------------------------------------------------
// deg histogram
// ---------------------------------------------------------------------------
__global__ void count_deg_kernel(const int* __restrict__ ea, const int* __restrict__ ep,
                                 int E, int* __restrict__ degA, int* __restrict__ degP) {
    int stride = gridDim.x * blockDim.x;
    for (int e = blockIdx.x * blockDim.x + threadIdx.x; e < E; e += stride) {
        atomicAdd(&degA[ea[e]], 1);
        atomicAdd(&degP[ep[e]], 1);
    }
}

// ---------------------------------------------------------------------------
// 3-pass device-wide exclusive scan over BOTH deg arrays
// ---------------------------------------------------------------------------
__global__ __launch_bounds__(256) void scan_partials_kernel(
        const int* __restrict__ degA, int nA,
        const int* __restrict__ degP, int nP, int gA,
        int* __restrict__ partials) {
    const int* deg; int n;
    int b = blockIdx.x;
    if (b < gA) { deg = degA; n = nA; }
    else        { deg = degP; n = nP; b -= gA; }
    int tid = threadIdx.x;
    int i0 = b * SCAN_TILE + tid * 4;
    int s = 0;
    if (i0 + 3 < n) {
        int4 d = *(const int4*)(deg + i0);
        s = d.x + d.y + d.z + d.w;
    } else {
        for (int j = 0; j < 4; ++j) if (i0 + j < n) s += deg[i0 + j];
    }
#pragma unroll
    for (int off = 32; off; off >>= 1) s += __shfl_xor(s, off);
    __shared__ int wsum[4];
    if ((tid & 63) == 0) wsum[tid >> 6] = s;
    __syncthreads();
    if (tid == 0) partials[blockIdx.x] = wsum[0] + wsum[1] + wsum[2] + wsum[3];
}

__global__ __launch_bounds__(1024) void scan_block_sums_kernel(
        int* __restrict__ partials, int gA, int gP,
        int* __restrict__ rsA_end, int* __restrict__ rsP_end) {
    __shared__ int s[1024];
    int n = gA + gP;
    int tid = threadIdx.x;
    int v = (tid < n) ? partials[tid] : 0;
    s[tid] = v;
    __syncthreads();
    for (int off = 1; off < 1024; off <<= 1) {
        int add = 0;
        if (tid >= off && ((tid < gA) || (tid - off >= gA))) add = s[tid - off];
        __syncthreads();
        s[tid] += add;
        __syncthreads();
    }
    if (tid == gA - 1)  *rsA_end = s[tid];
    if (tid == n - 1)   *rsP_end = s[tid];
    if (tid < n) partials[tid] = s[tid] - v;
}

__global__ __launch_bounds__(256) void scan_write_kernel(
        const int* __restrict__ degA, int nA, int* __restrict__ rsA,
        const int* __restrict__ degP, int nP, int* __restrict__ rsP,
        int gA, const int* __restrict__ partials) {
    const int* deg; int n; int* rs;
    int b = blockIdx.x;
    int part = partials[blockIdx.x];
    if (b < gA) { deg = degA; n = nA; rs = rsA; }
    else        { deg = degP; n = nP; rs = rsP; b -= gA; }
    int tid = threadIdx.x;
    int lane = tid & 63, wid = tid >> 6;
    int i0 = b * SCAN_TILE + tid * 4;

    int4 d = make_int4(0, 0, 0, 0);
    if (i0 + 3 < n) {
        d = *(const int4*)(deg + i0);
    } else {
        if (i0 + 0 < n) d.x = deg[i0 + 0];
        if (i0 + 1 < n) d.y = deg[i0 + 1];
        if (i0 + 2 < n) d.z = deg[i0 + 2];
        if (i0 + 3 < n) d.w = deg[i0 + 3];
    }
    int tsum = d.x + d.y + d.z + d.w;

    int x = tsum;
#pragma unroll
    for (int off = 1; off < 64; off <<= 1) {
        int y = __shfl_up(x, off);
        if (lane >= off) x += y;
    }
    int excl = x - tsum;

    __shared__ int wsum[4];
    if (lane == 63) wsum[wid] = x;
    __syncthreads();
    int woff = 0;
#pragma unroll
    for (int w = 0; w < 4; ++w) if (w < wid) woff += wsum[w];

    int off0 = part + woff + excl;
    int4 o;
    o.x = off0;
    o.y = off0 + d.x;
    o.z = o.y + d.y;
    o.w = o.z + d.z;
    if (i0 + 3 < n) {
        *(int4*)(rs + i0) = o;
    } else {
        if (i0 + 0 < n) rs[i0 + 0] = o.x;
        if (i0 + 1 < n) rs[i0 + 1] = o.y;
        if (i0 + 2 < n) rs[i0 + 2] = o.z;
        if (i0 + 3 < n) rs[i0 + 3] = o.w;
    }
}

// ---------------------------------------------------------------------------
// coarse cursor init
// ---------------------------------------------------------------------------
__global__ __launch_bounds__(256) void gcur_init_kernel(
        const int* __restrict__ rsA, int nbcA,
        const int* __restrict__ rsP, int nbc, int E, int* __restrict__ gcur) {
    int i = blockIdx.x * blockDim.x + threadIdx.x;
    if (i < nbcA)                gcur[i] = rsA[i << CB_SHIFT];
    else if (i < nbc)            gcur[i] = E + rsP[(i - nbcA) << CB_SHIFT];
}

// ---------------------------------------------------------------------------
// LDS multisplit (block-owned contiguous runs per coarse bucket)
// ---------------------------------------------------------------------------
__global__ __launch_bounds__(256) void multisplit_kernel(
        const int* __restrict__ ea, const int* __restrict__ ep, int E,
        int nbcA, int* __restrict__ gcur, unsigned* __restrict__ buf) {
    __shared__ int hist[256];
    __shared__ int off[256];
    __shared__ int cnt2[256];
    __shared__ int gbase[256];
    __shared__ unsigned cbuf[2 * CHE];
    __shared__ unsigned char bkt[2 * CHE];

    int tid = threadIdx.x;
    int e0 = blockIdx.x * CHE;
    int ecnt = E - e0; if (ecnt > CHE) ecnt = CHE;

    hist[tid] = 0;
    __syncthreads();

    for (int k = tid; k < ecnt; k += 256) {
        int a = ea[e0 + k], p = ep[e0 + k];
        atomicAdd(&hist[a >> CB_SHIFT], 1);
        atomicAdd(&hist[nbcA + (p >> CB_SHIFT)], 1);
    }
    __syncthreads();

    int v = hist[tid];
    off[tid] = v;
    __syncthreads();
    for (int o = 1; o < 256; o <<= 1) {
        int y = (tid >= o) ? off[tid - o] : 0;
        __syncthreads();
        off[tid] += y;
        __syncthreads();
    }
    int excl = off[tid] - v;
    off[tid] = excl;
    cnt2[tid] = 0;
    if (v > 0) gbase[tid] = atomicAdd(&gcur[tid], v);
    __syncthreads();

    for (int k = tid; k < ecnt; k += 256) {
        int a = ea[e0 + k], p = ep[e0 + k];
        int bA = a >> CB_SHIFT;
        int iA = off[bA] + atomicAdd(&cnt2[bA], 1);
        cbuf[iA] = ((unsigned)p << CB_SHIFT) | (unsigned)(a & (CB_NODES - 1));
        bkt[iA] = (unsigned char)bA;
        int bP = nbcA + (p >> CB_SHIFT);
        int iP = off[bP] + atomicAdd(&cnt2[bP], 1);
        cbuf[iP] = ((unsigned)a << CB_SHIFT) | (unsigned)(p & (CB_NODES - 1));
        bkt[iP] = (unsigned char)bP;
    }
    __syncthreads();

    int total = 2 * ecnt;
    for (int i = tid; i < total; i += 256) {
        int b = bkt[i];
        buf[(size_t)gbase[b] + (i - off[b])] = cbuf[i];
    }
}

// ---------------------------------------------------------------------------
// fine sort: one block per coarse bucket
// ---------------------------------------------------------------------------
__global__ __launch_bounds__(1024) void fine_csr_kernel(
        const int* __restrict__ rsA, int nA, int nbcA, int* __restrict__ csrA,
        const int* __restrict__ rsP, int nP, int* __restrict__ csrP,
        const unsigned* __restrict__ buf, int E) {
    __shared__ int base[CB_NODES + 1];
    __shared__ int cnt[CB_NODES];
    const int* rs; int* csr; int n; int d0; const unsigned* mybuf;
    int b = blockIdx.x;
    if (b < nbcA) { rs = rsA; csr = csrA; n = nA; d0 = b << CB_SHIFT; mybuf = buf; }
    else { rs = rsP; csr = csrP; n = nP; d0 = (b - nbcA) << CB_SHIFT; mybuf = buf + E; }
    int nd = n - d0; if (nd > CB_NODES) nd = CB_NODES;

    int tid = threadIdx.x;
    for (int i = tid; i <= nd; i += 1024) base[i] = rs[d0 + i];
    for (int i = tid; i < nd; i += 1024) cnt[i] = 0;
    __syncthreads();

    int g0 = base[0], g1 = base[nd];
    for (int j = g0 + tid; j < g1; j += 1024) {
        unsigned pk = mybuf[j];
        int li = pk & (CB_NODES - 1);
        int src = (int)(pk >> CB_SHIFT);
        int pos = base[li] + atomicAdd(&cnt[li], 1);
        csr[pos] = src;
    }
}

// ---------------------------------------------------------------------------
// W pre-pack (unchanged)
// ---------------------------------------------------------------------------
__global__ __launch_bounds__(256) void pack_w_kernel(
        const float* __restrict__ WsA, const float* __restrict__ WsP,
        const float* __restrict__ Wa2p, const float* __restrict__ Wp2a,
        unsigned short* __restrict__ Bpack) {
    int combo = blockIdx.x >> 4;
    int e = (blockIdx.x & 15) * 256 + threadIdx.x;   // 0..4095
    int layer = combo >> 1;
    const float* Ws = ((combo & 1) ? WsP : WsA) + (size_t)layer * D * D;
    const float* Wm = ((combo & 1) ? Wa2p : Wp2a) + (size_t)layer * D * D;

    int f = e >> 6, lane = e & 63;
    int nf = f >> 3, ks = f & 7;
    int k0 = ks * 32 + (lane >> 4) * 8;
    int col = nf * 16 + (lane & 15);

    unsigned short v[8];
#pragma unroll
    for (int j = 0; j < 8; ++j) {
        int k = k0 + j;
        float x = (k < D) ? Ws[(size_t)k * D + col] : Wm[(size_t)(k - D) * D + col];
        v[j] = f2bf(x);
    }
    uint4 o;
    o.x = v[0] | ((unsigned)v[1] << 16);
    o.y = v[2] | ((unsigned)v[3] << 16);
    o.z = v[4] | ((unsigned)v[5] << 16);
    o.w = v[6] | ((unsigned)v[7] << 16);
    *(uint4*)(Bpack + (size_t)combo * 32768 + (size_t)e * 8) = o;
}

// ---------------------------------------------------------------------------
// bf16 pull-aggregation, BOTH directions in one launch.
// One wave per dst row; 4x16-lane subwaves each load a full 256B row.
// ---------------------------------------------------------------------------
__global__ __launch_bounds__(256) void aggregate_duo(
        const unsigned short* __restrict__ srcA, const int* __restrict__ rsA,
        const int* __restrict__ csrA, int nA, unsigned short* __restrict__ aggA,
        const unsigned short* __restrict__ srcP, const int* __restrict__ rsP,
        const int* __restrict__ csrP, int nP, unsigned short* __restrict__ aggP) {
    int gw   = (blockIdx.x * 256 + threadIdx.x) >> 6;
    int lane = threadIdx.x & 63;
    int sub  = lane >> 4;
    int sl   = lane & 15;

    const unsigned short* xsrc; const int* rs; const int* csr;
    unsigned short* agg; int d;
    if (gw < nA) { d = gw;      xsrc = srcA; rs = rsA; csr = csrA; agg = aggA; }
    else {
        d = gw - nA;
        if (d >= nP) return;
        xsrc = srcP; rs = rsP; csr = csrP; agg = aggP;
    }

    int s0 = rs[d], s1 = rs[d + 1];
    float acc[8] = {0.f, 0.f, 0.f, 0.f, 0.f, 0.f, 0.f, 0.f};
    for (int j = s0 + sub; j < s1; j += 4) {
        int s = csr[j];
        uint4 v = *(const uint4*)(xsrc + (size_t)s * D + sl * 8);
        acc[0] += bflo(v.x); acc[1] += bfhi(v.x);
        acc[2] += bflo(v.y); acc[3] += bfhi(v.y);
        acc[4] += bflo(v.z); acc[5] += bfhi(v.z);
        acc[6] += bflo(v.w); acc[7] += bfhi(v.w);
    }
#pragma unroll
    for (int i = 0; i < 8; ++i) {
        acc[i] += __shfl_xor(acc[i], 16);
        acc[i] += __shfl_xor(acc[i], 32);
    }
    if (sub == 0) {
        uint4 o;
        o.x = f2bf(acc[0]) | ((unsigned)f2bf(acc[1]) << 16);
        o.y = f2bf(acc[2]) | ((unsigned)f2bf(acc[3]) << 16);
        o.z = f2bf(acc[4]) | ((unsigned)f2bf(acc[5]) << 16);
        o.w = f2bf(acc[6]) | ((unsigned)f2bf(acc[7]) << 16);
        *(uint4*)(agg + (size_t)d * D + sl * 8) = o;
    }
}

// ---------------------------------------------------------------------------
// MFMA node update, BOTH sides in one launch, with register double-buffered
// B fragments: preload all 8 b[ks] of column-block nf+1 while nf's MFMA chain
// runs -> 8 L2 loads in flight instead of ~1 (VGPR 48 starved the ILP).
// ---------------------------------------------------------------------------
__global__ __launch_bounds__(256) void linear_mfma_duo(
        const unsigned short* __restrict__ xsA, const unsigned short* __restrict__ xmA,
        const unsigned short* __restrict__ BpA, const float* __restrict__ bsA,
        const float* __restrict__ bmA, const int* __restrict__ degA_, int nA,
        unsigned short* __restrict__ outA, int gmA,
        const unsigned short* __restrict__ xsP, const unsigned short* __restrict__ xmP,
        const unsigned short* __restrict__ BpP, const float* __restrict__ bsP,
        const float* __restrict__ bmP, const int* __restrict__ degP_, int nP,
        unsigned short* __restrict__ outP, int relu) {
    __shared__ uint4 lds4[2048];   // 32 KB
    unsigned char* lds = (unsigned char*)lds4;
    int tid = threadIdx.x;
    int wave = tid >> 6, lane = tid & 63;

    const unsigned short *xs, *xm, *Bpack; const float *bs, *bm;
    const int* deg; int n; unsigned short* out;
    int b = blockIdx.x;
    if (b < gmA) { xs = xsA; xm = xmA; Bpack = BpA; bs = bsA; bm = bmA;
                   deg = degA_; n = nA; out = outA; }
    else { b -= gmA; xs = xsP; xm = xmP; Bpack = BpP; bs = bsP; bm = bmP;
           deg = degP_; n = nP; out = outP; }
    int r_base = b * 64;

    // ---- stage [xs|xm] tile (swizzled) ----
#pragma unroll
    for (int i = 0; i < 8; ++i) {
        int c = i * 256 + tid;        // 0..2047
        int row = c >> 5;             // 0..63
        int kc = (c & 31) * 8;        // bf16 elem offset 0..248
        int rg = r_base + row;
        uint4 w = make_uint4(0, 0, 0, 0);
        if (rg < n) {
            const unsigned short* src = (kc < D) ? (xs + (size_t)rg * D + kc)
                                                 : (xm + (size_t)rg * D + (kc - D));
            w = *(const uint4*)src;
        }
        unsigned addr = ((unsigned)(row * 512 + kc * 2)) ^ ((unsigned)((row & 7) << 4));
        *(uint4*)(lds + addr) = w;
    }
    __syncthreads();

    // ---- A fragments ----
    int lrow = wave * 16 + (lane & 15);
    bf16x8_t a[8];
#pragma unroll
    for (int ks = 0; ks < 8; ++ks) {
        unsigned addr = ((unsigned)(lrow * 512 + ks * 64 + (lane >> 4) * 16))
                        ^ ((unsigned)((lrow & 7) << 4));
        a[ks] = *(const bf16x8_t*)(lds + addr);
    }

    // ---- MFMA main loop with B register double-buffer ----
    f32x4_t acc[8];
#pragma unroll
    for (int nf = 0; nf < 8; ++nf) acc[nf] = (f32x4_t){0.f, 0.f, 0.f, 0.f};

    const bf16x8_t* bp = (const bf16x8_t*)Bpack;
    bf16x8_t bcur[8], bnxt[8];
#pragma unroll
    for (int ks = 0; ks < 8; ++ks) bcur[ks] = bp[ks * 64 + lane];

#pragma unroll
    for (int nf = 0; nf < 8; ++nf) {
        if (nf < 7) {
#pragma unroll
            for (int ks = 0; ks < 8; ++ks)
                bnxt[ks] = bp[((nf + 1) * 8 + ks) * 64 + lane];
        }
#pragma unroll
        for (int ks = 0; ks < 8; ++ks)
            acc[nf] = __builtin_amdgcn_mfma_f32_16x16x32_bf16(a[ks], bcur[ks], acc[nf], 0, 0, 0);
#pragma unroll
        for (int ks = 0; ks < 8; ++ks) bcur[ks] = bnxt[ks];
    }

    // ---- epilogue ----
    int rb2 = r_base + wave * 16 + (lane >> 4) * 4;
    float dg[4];
#pragma unroll
    for (int rr = 0; rr < 4; ++rr)
        dg[rr] = (rb2 + rr < n) ? (float)deg[rb2 + rr] : 0.f;

#pragma unroll
    for (int nf = 0; nf < 8; ++nf) {
        int col = nf * 16 + (lane & 15);
        float bsv = bs[col], bmv = bm[col];
#pragma unroll
        for (int rr = 0; rr < 4; ++rr) {
            int r = rb2 + rr;
            if (r < n) {
                float v = acc[nf][rr] + bsv + dg[rr] * bmv;
                if (relu) v = fmaxf(v, 0.f);
                out[(size_t)r * D + col] = f2bf(v);
            }
        }
    }
}

// ---------------------------------------------------------------------------
// supervision dot products on bf16 embeddings
// ---------------------------------------------------------------------------
__global__ __launch_bounds__(256) void dot_kernel(
        const unsigned short* __restrict__ za, const unsigned short* __restrict__ zp,
        const int* __restrict__ sa, const int* __restrict__ sp, int S,
        float* __restrict__ out) {
    int gw   = (blockIdx.x * 256 + threadIdx.x) >> 6;
    int lane = threadIdx.x & 63;
    int nw   = (gridDim.x * 256) >> 6;
    for (int i = gw; i < S; i += nw) {
        int a = sa[i], p = sp[i];
        unsigned ua = *(const unsigned*)(za + (size_t)a * D + lane * 2);
        unsigned up = *(const unsigned*)(zp + (size_t)p * D + lane * 2);
        float s = bflo(ua) * bflo(up) + bfhi(ua) * bfhi(up);
#pragma unroll
        for (int off = 32; off > 0; off >>= 1) s += __shfl_xor(s, off);
        if (lane == 0) out[i] = s;
    }
}

// ---------------------------------------------------------------------------
extern "C" void kernel_launch(void* const* d_in, const int* in_sizes, int n_in,
                              void* d_out, int out_size, void* d_ws, size_t ws_size,
                              hipStream_t stream) {
    const float* x_a  = (const float*)d_in[0];
    const float* x_p  = (const float*)d_in[1];
    const int*   ea   = (const int*)d_in[2];
    const int*   ep   = (const int*)d_in[3];
    const int*   sa   = (const int*)d_in[4];
    const int*   sp   = (const int*)d_in[5];
    const float* WsA  = (const float*)d_in[6];
    const float* bsA  = (const float*)d_in[7];
    const float* WsP  = (const float*)d_in[8];
    const float* bsP  = (const float*)d_in[9];
    const float* Wa2p = (const float*)d_in[10];
    const float* ba2p = (const float*)d_in[11];
    const float* Wp2a = (const float*)d_in[12];
    const float* bp2a = (const float*)d_in[13];

    const int nA = in_sizes[0] / D;   // 100000
    const int nP = in_sizes[1] / D;   // 200000
    const int E  = in_sizes[2];       // 600000
    const int S  = in_sizes[4];       // 100000

    // ---- workspace layout ----
    char* ws = (char*)d_ws;
    size_t curoff = 0;
    auto alloc = [&](size_t bytes) -> void* {
        void* p = ws + curoff;
        curoff = (curoff + bytes + 255) & ~(size_t)255;
        return p;
    };
    unsigned short* xb_a  = (unsigned short*)alloc((size_t)nA * D * 2);
    unsigned short* xb_p  = (unsigned short*)alloc((size_t)nP * D * 2);
    unsigned short* agg_a = (unsigned short*)alloc((size_t)nA * D * 2);
    unsigned short* agg_p = (unsigned short*)alloc((size_t)nP * D * 2);
    unsigned short* y_a   = (unsigned short*)alloc((size_t)nA * D * 2);
    unsigned short* y_p   = (unsigned short*)alloc((size_t)nP * D * 2);
    unsigned short* z_a   = (unsigned short*)alloc((size_t)nA * D * 2);
    unsigned short* z_p   = (unsigned short*)alloc((size_t)nP * D * 2);
    int* degA = (int*)alloc((size_t)nA * 4);
    int* degP = (int*)alloc((size_t)nP * 4);
    int* rsA  = (int*)alloc(((size_t)nA + 1) * 4);
    int* rsP  = (int*)alloc(((size_t)nP + 1) * 4);
    int* csrA = (int*)alloc((size_t)E * 4);
    int* csrP = (int*)alloc((size_t)E * 4);
    const int gA = (nA + SCAN_TILE - 1) / SCAN_TILE;
    const int gP = (nP + SCAN_TILE - 1) / SCAN_TILE;
    int* partials = (int*)alloc((size_t)(gA + gP) * 4);
    unsigned short* Bpack = (unsigned short*)alloc((size_t)4 * 32768 * 2);  // 256 KB

    // multisplit structures alias z_a/z_p (preprocessing ends before layer 1)
    const int nbcA = (nA + CB_NODES - 1) >> CB_SHIFT;   // 49
    const int nbcP = (nP + CB_NODES - 1) >> CB_SHIFT;   // 98
    const int NBC  = nbcA + nbcP;                       // 147
    unsigned* buf = (unsigned*)z_a;           // 2E*4 = 4.8 MB
    int* gcur = (int*)z_p;                    // NBC ints

    // ---- bf16 input copies + graph preprocessing + W packing ----
    f32_to_bf16_duo<<<3072, 256, 0, stream>>>(x_a, xb_a, nA * D / 8,
                                              x_p, xb_p, nP * D / 8);
    size_t deg_bytes = (size_t)((char*)degP - (char*)degA) + (size_t)nP * 4;
    hipMemsetAsync(degA, 0, deg_bytes, stream);
    pack_w_kernel<<<64, 256, 0, stream>>>(WsA, WsP, Wa2p, Wp2a, Bpack);
    count_deg_kernel<<<1024, 256, 0, stream>>>(ea, ep, E, degA, degP);
    scan_partials_kernel<<<gA + gP, 256, 0, stream>>>(degA, nA, degP, nP, gA, partials);
    scan_block_sums_kernel<<<1, 1024, 0, stream>>>(partials, gA, gP, rsA + nA, rsP + nP);
    scan_write_kernel<<<gA + gP, 256, 0, stream>>>(degA, nA, rsA,
                                                   degP, nP, rsP, gA, partials);
    gcur_init_kernel<<<1, 256, 0, stream>>>(rsA, nbcA, rsP, NBC, E, gcur);
    multisplit_kernel<<<(E + CHE - 1) / CHE, 256, 0, stream>>>(ea, ep, E, nbcA, gcur, buf);
    fine_csr_kernel<<<NBC, 1024, 0, stream>>>(rsA, nA, nbcA, csrA,
                                              rsP, nP, csrP, buf, E);

    const int gmA = (nA + 63) / 64;   // 1563
    const int gmP = (nP + 63) / 64;   // 3125
    const int gAgg = (nA + nP + 3) / 4;   // one wave per dst row, both sides

    // ---- layer 0 (relu) ----
    aggregate_duo<<<gAgg, 256, 0, stream>>>(xb_p, rsA, csrA, nA, agg_a,
                                            xb_a, rsP, csrP, nP, agg_p);
    linear_mfma_duo<<<gmA + gmP, 256, 0, stream>>>(
        xb_a, agg_a, Bpack + 0 * 32768, bsA, bp2a, degA, nA, y_a, gmA,
        xb_p, agg_p, Bpack + 1 * 32768, bsP, ba2p, degP, nP, y_p, 1);

    // ---- layer 1 (no relu) ----
    aggregate_duo<<<gAgg, 256, 0, stream>>>(y_p, rsA, csrA, nA, agg_a,
                                            y_a, rsP, csrP, nP, agg_p);
    linear_mfma_duo<<<gmA + gmP, 256, 0, stream>>>(
        y_a, agg_a, Bpack + 2 * 32768, bsA + D, bp2a + D, degA, nA, z_a, gmA,
        y_p, agg_p, Bpack + 3 * 32768, bsP + D, ba2p + D, degP, nP, z_p, 0);

    // ---- supervision scores ----
    dot_kernel<<<(S + 3) / 4, 256, 0, stream>>>(z_a, z_p, sa, sp, S, (float*)d_out);
}

// Round 9
// 516.792 us; speedup vs baseline: 1.2184x; 1.0016x over previous
//
#include <hip/hip_runtime.h>
#include <stdint.h>

#define D 128
#define SCAN_TILE 1024  // elements per scan block (256 thr x 4)
#define CB_SHIFT 11     // coarse bucket = 2048 dst nodes
#define CB_NODES 2048
#define CHE 2048        // edges per multisplit chunk (2*CHE entries)

typedef __attribute__((ext_vector_type(8))) short bf16x8_t;
typedef __attribute__((ext_vector_type(4))) float f32x4_t;

__device__ inline unsigned short f2bf(float x) {
    unsigned int u = __float_as_uint(x);
    unsigned int r = (u + 0x7fffu + ((u >> 16) & 1u)) >> 16;   // RNE
    return (unsigned short)r;
}
__device__ inline float bflo(unsigned v) { return __uint_as_float(v << 16); }
__device__ inline float bfhi(unsigned v) { return __uint_as_float(v & 0xffff0000u); }

// ---------------------------------------------------------------------------
// f32 -> bf16 bulk convert, both arrays in one launch
// ---------------------------------------------------------------------------
__global__ __launch_bounds__(256) void f32_to_bf16_duo(
        const float* __restrict__ inA, unsigned short* __restrict__ outA, int n8A,
        const float* __restrict__ inP, unsigned short* __restrict__ outP, int n8P) {
    int stride = gridDim.x * blockDim.x;
    int total = n8A + n8P;
    for (int i = blockIdx.x * blockDim.x + threadIdx.x; i < total; i += stride) {
        const float* in; unsigned short* out; int j;
        if (i < n8A) { in = inA; out = outA; j = i; }
        else         { in = inP; out = outP; j = i - n8A; }
        float4 v0 = *(const float4*)(in + (size_t)j * 8);
        float4 v1 = *(const float4*)(in + (size_t)j * 8 + 4);
        uint4 o;
        o.x = f2bf(v0.x) | ((unsigned)f2bf(v0.y) << 16);
        o.y = f2bf(v0.z) | ((unsigned)f2bf(v0.w) << 16);
        o.z = f2bf(v1.x) | ((unsigned)f2bf(v1.y) << 16);
        o.w = f2bf(v1.z) | ((unsigned)f2bf(v1.w) << 16);
        *(uint4*)(out + (size_t)j * 8) = o;
    }
}

// ---------------------------------------------------------------------------
// deg histogram
// ---------------------------------------------------------------------------
__global__ void count_deg_kernel(const int* __restrict__ ea, const int* __restrict__ ep,
                                 int E, int* __restrict__ degA, int* __restrict__ degP) {
    int stride = gridDim.x * blockDim.x;
    for (int e = blockIdx.x * blockDim.x + threadIdx.x; e < E; e += stride) {
        atomicAdd(&degA[ea[e]], 1);
        atomicAdd(&degP[ep[e]], 1);
    }
}

// ---------------------------------------------------------------------------
// 3-pass device-wide exclusive scan over BOTH deg arrays
// ---------------------------------------------------------------------------
__global__ __launch_bounds__(256) void scan_partials_kernel(
        const int* __restrict__ degA, int nA,
        const int* __restrict__ degP, int nP, int gA,
        int* __restrict__ partials) {
    const int* deg; int n;
    int b = blockIdx.x;
    if (b < gA) { deg = degA; n = nA; }
    else        { deg = degP; n = nP; b -= gA; }
    int tid = threadIdx.x;
    int i0 = b * SCAN_TILE + tid * 4;
    int s = 0;
    if (i0 + 3 < n) {
        int4 d = *(const int4*)(deg + i0);
        s = d.x + d.y + d.z + d.w;
    } else {
        for (int j = 0; j < 4; ++j) if (i0 + j < n) s += deg[i0 + j];
    }
#pragma unroll
    for (int off = 32; off; off >>= 1) s += __shfl_xor(s, off);
    __shared__ int wsum[4];
    if ((tid & 63) == 0) wsum[tid >> 6] = s;
    __syncthreads();
    if (tid == 0) partials[blockIdx.x] = wsum[0] + wsum[1] + wsum[2] + wsum[3];
}

__global__ __launch_bounds__(1024) void scan_block_sums_kernel(
        int* __restrict__ partials, int gA, int gP,
        int* __restrict__ rsA_end, int* __restrict__ rsP_end) {
    __shared__ int s[1024];
    int n = gA + gP;
    int tid = threadIdx.x;
    int v = (tid < n) ? partials[tid] : 0;
    s[tid] = v;
    __syncthreads();
    for (int off = 1; off < 1024; off <<= 1) {
        int add = 0;
        if (tid >= off && ((tid < gA) || (tid - off >= gA))) add = s[tid - off];
        __syncthreads();
        s[tid] += add;
        __syncthreads();
    }
    if (tid == gA - 1)  *rsA_end = s[tid];
    if (tid == n - 1)   *rsP_end = s[tid];
    if (tid < n) partials[tid] = s[tid] - v;
}

__global__ __launch_bounds__(256) void scan_write_kernel(
        const int* __restrict__ degA, int nA, int* __restrict__ rsA,
        const int* __restrict__ degP, int nP, int* __restrict__ rsP,
        int gA, const int* __restrict__ partials) {
    const int* deg; int n; int* rs;
    int b = blockIdx.x;
    int part = partials[blockIdx.x];
    if (b < gA) { deg = degA; n = nA; rs = rsA; }
    else        { deg = degP; n = nP; rs = rsP; b -= gA; }
    int tid = threadIdx.x;
    int lane = tid & 63, wid = tid >> 6;
    int i0 = b * SCAN_TILE + tid * 4;

    int4 d = make_int4(0, 0, 0, 0);
    if (i0 + 3 < n) {
        d = *(const int4*)(deg + i0);
    } else {
        if (i0 + 0 < n) d.x = deg[i0 + 0];
        if (i0 + 1 < n) d.y = deg[i0 + 1];
        if (i0 + 2 < n) d.z = deg[i0 + 2];
        if (i0 + 3 < n) d.w = deg[i0 + 3];
    }
    int tsum = d.x + d.y + d.z + d.w;

    int x = tsum;
#pragma unroll
    for (int off = 1; off < 64; off <<= 1) {
        int y = __shfl_up(x, off);
        if (lane >= off) x += y;
    }
    int excl = x - tsum;

    __shared__ int wsum[4];
    if (lane == 63) wsum[wid] = x;
    __syncthreads();
    int woff = 0;
#pragma unroll
    for (int w = 0; w < 4; ++w) if (w < wid) woff += wsum[w];

    int off0 = part + woff + excl;
    int4 o;
    o.x = off0;
    o.y = off0 + d.x;
    o.z = o.y + d.y;
    o.w = o.z + d.z;
    if (i0 + 3 < n) {
        *(int4*)(rs + i0) = o;
    } else {
        if (i0 + 0 < n) rs[i0 + 0] = o.x;
        if (i0 + 1 < n) rs[i0 + 1] = o.y;
        if (i0 + 2 < n) rs[i0 + 2] = o.z;
        if (i0 + 3 < n) rs[i0 + 3] = o.w;
    }
}

// ---------------------------------------------------------------------------
// coarse cursor init
// ---------------------------------------------------------------------------
__global__ __launch_bounds__(256) void gcur_init_kernel(
        const int* __restrict__ rsA, int nbcA,
        const int* __restrict__ rsP, int nbc, int E, int* __restrict__ gcur) {
    int i = blockIdx.x * blockDim.x + threadIdx.x;
    if (i < nbcA)                gcur[i] = rsA[i << CB_SHIFT];
    else if (i < nbc)            gcur[i] = E + rsP[(i - nbcA) << CB_SHIFT];
}

// ---------------------------------------------------------------------------
// LDS multisplit (block-owned contiguous runs per coarse bucket)
// ---------------------------------------------------------------------------
__global__ __launch_bounds__(256) void multisplit_kernel(
        const int* __restrict__ ea, const int* __restrict__ ep, int E,
        int nbcA, int* __restrict__ gcur, unsigned* __restrict__ buf) {
    __shared__ int hist[256];
    __shared__ int off[256];
    __shared__ int cnt2[256];
    __shared__ int gbase[256];
    __shared__ unsigned cbuf[2 * CHE];
    __shared__ unsigned char bkt[2 * CHE];

    int tid = threadIdx.x;
    int e0 = blockIdx.x * CHE;
    int ecnt = E - e0; if (ecnt > CHE) ecnt = CHE;

    hist[tid] = 0;
    __syncthreads();

    for (int k = tid; k < ecnt; k += 256) {
        int a = ea[e0 + k], p = ep[e0 + k];
        atomicAdd(&hist[a >> CB_SHIFT], 1);
        atomicAdd(&hist[nbcA + (p >> CB_SHIFT)], 1);
    }
    __syncthreads();

    int v = hist[tid];
    off[tid] = v;
    __syncthreads();
    for (int o = 1; o < 256; o <<= 1) {
        int y = (tid >= o) ? off[tid - o] : 0;
        __syncthreads();
        off[tid] += y;
        __syncthreads();
    }
    int excl = off[tid] - v;
    off[tid] = excl;
    cnt2[tid] = 0;
    if (v > 0) gbase[tid] = atomicAdd(&gcur[tid], v);
    __syncthreads();

    for (int k = tid; k < ecnt; k += 256) {
        int a = ea[e0 + k], p = ep[e0 + k];
        int bA = a >> CB_SHIFT;
        int iA = off[bA] + atomicAdd(&cnt2[bA], 1);
        cbuf[iA] = ((unsigned)p << CB_SHIFT) | (unsigned)(a & (CB_NODES - 1));
        bkt[iA] = (unsigned char)bA;
        int bP = nbcA + (p >> CB_SHIFT);
        int iP = off[bP] + atomicAdd(&cnt2[bP], 1);
        cbuf[iP] = ((unsigned)a << CB_SHIFT) | (unsigned)(p & (CB_NODES - 1));
        bkt[iP] = (unsigned char)bP;
    }
    __syncthreads();

    int total = 2 * ecnt;
    for (int i = tid; i < total; i += 256) {
        int b = bkt[i];
        buf[(size_t)gbase[b] + (i - off[b])] = cbuf[i];
    }
}

// ---------------------------------------------------------------------------
// fine sort: one block per coarse bucket
// ---------------------------------------------------------------------------
__global__ __launch_bounds__(1024) void fine_csr_kernel(
        const int* __restrict__ rsA, int nA, int nbcA, int* __restrict__ csrA,
        const int* __restrict__ rsP, int nP, int* __restrict__ csrP,
        const unsigned* __restrict__ buf, int E) {
    __shared__ int base[CB_NODES + 1];
    __shared__ int cnt[CB_NODES];
    const int* rs; int* csr; int n; int d0; const unsigned* mybuf;
    int b = blockIdx.x;
    if (b < nbcA) { rs = rsA; csr = csrA; n = nA; d0 = b << CB_SHIFT; mybuf = buf; }
    else { rs = rsP; csr = csrP; n = nP; d0 = (b - nbcA) << CB_SHIFT; mybuf = buf + E; }
    int nd = n - d0; if (nd > CB_NODES) nd = CB_NODES;

    int tid = threadIdx.x;
    for (int i = tid; i <= nd; i += 1024) base[i] = rs[d0 + i];
    for (int i = tid; i < nd; i += 1024) cnt[i] = 0;
    __syncthreads();

    int g0 = base[0], g1 = base[nd];
    for (int j = g0 + tid; j < g1; j += 1024) {
        unsigned pk = mybuf[j];
        int li = pk & (CB_NODES - 1);
        int src = (int)(pk >> CB_SHIFT);
        int pos = base[li] + atomicAdd(&cnt[li], 1);
        csr[pos] = src;
    }
}

// ---------------------------------------------------------------------------
// W pre-pack (unchanged)
// ---------------------------------------------------------------------------
__global__ __launch_bounds__(256) void pack_w_kernel(
        const float* __restrict__ WsA, const float* __restrict__ WsP,
        const float* __restrict__ Wa2p, const float* __restrict__ Wp2a,
        unsigned short* __restrict__ Bpack) {
    int combo = blockIdx.x >> 4;
    int e = (blockIdx.x & 15) * 256 + threadIdx.x;   // 0..4095
    int layer = combo >> 1;
    const float* Ws = ((combo & 1) ? WsP : WsA) + (size_t)layer * D * D;
    const float* Wm = ((combo & 1) ? Wa2p : Wp2a) + (size_t)layer * D * D;

    int f = e >> 6, lane = e & 63;
    int nf = f >> 3, ks = f & 7;
    int k0 = ks * 32 + (lane >> 4) * 8;
    int col = nf * 16 + (lane & 15);

    unsigned short v[8];
#pragma unroll
    for (int j = 0; j < 8; ++j) {
        int k = k0 + j;
        float x = (k < D) ? Ws[(size_t)k * D + col] : Wm[(size_t)(k - D) * D + col];
        v[j] = f2bf(x);
    }
    uint4 o;
    o.x = v[0] | ((unsigned)v[1] << 16);
    o.y = v[2] | ((unsigned)v[3] << 16);
    o.z = v[4] | ((unsigned)v[5] << 16);
    o.w = v[6] | ((unsigned)v[7] << 16);
    *(uint4*)(Bpack + (size_t)combo * 32768 + (size_t)e * 8) = o;
}

// ---------------------------------------------------------------------------
// bf16 pull-aggregation, BOTH directions in one launch.
// ---------------------------------------------------------------------------
__global__ __launch_bounds__(256) void aggregate_duo(
        const unsigned short* __restrict__ srcA, const int* __restrict__ rsA,
        const int* __restrict__ csrA, int nA, unsigned short* __restrict__ aggA,
        const unsigned short* __restrict__ srcP, const int* __restrict__ rsP,
        const int* __restrict__ csrP, int nP, unsigned short* __restrict__ aggP) {
    int gw   = (blockIdx.x * 256 + threadIdx.x) >> 6;
    int lane = threadIdx.x & 63;
    int sub  = lane >> 4;
    int sl   = lane & 15;

    const unsigned short* xsrc; const int* rs; const int* csr;
    unsigned short* agg; int d;
    if (gw < nA) { d = gw;      xsrc = srcA; rs = rsA; csr = csrA; agg = aggA; }
    else {
        d = gw - nA;
        if (d >= nP) return;
        xsrc = srcP; rs = rsP; csr = csrP; agg = aggP;
    }

    int s0 = rs[d], s1 = rs[d + 1];
    float acc[8] = {0.f, 0.f, 0.f, 0.f, 0.f, 0.f, 0.f, 0.f};
    for (int j = s0 + sub; j < s1; j += 4) {
        int s = csr[j];
        uint4 v = *(const uint4*)(xsrc + (size_t)s * D + sl * 8);
        acc[0] += bflo(v.x); acc[1] += bfhi(v.x);
        acc[2] += bflo(v.y); acc[3] += bfhi(v.y);
        acc[4] += bflo(v.z); acc[5] += bfhi(v.z);
        acc[6] += bflo(v.w); acc[7] += bfhi(v.w);
    }
#pragma unroll
    for (int i = 0; i < 8; ++i) {
        acc[i] += __shfl_xor(acc[i], 16);
        acc[i] += __shfl_xor(acc[i], 32);
    }
    if (sub == 0) {
        uint4 o;
        o.x = f2bf(acc[0]) | ((unsigned)f2bf(acc[1]) << 16);
        o.y = f2bf(acc[2]) | ((unsigned)f2bf(acc[3]) << 16);
        o.z = f2bf(acc[4]) | ((unsigned)f2bf(acc[5]) << 16);
        o.w = f2bf(acc[6]) | ((unsigned)f2bf(acc[7]) << 16);
        *(uint4*)(agg + (size_t)d * D + sl * 8) = o;
    }
}

// ---------------------------------------------------------------------------
// MFMA node update, 128 rows/block (4 waves x 2 sub-tiles of 16 rows).
// Each B fragment now feeds 2 MFMAs -> B L2 traffic halves (1.2GB -> 600MB),
// the round-8 bottleneck. a[2][8] held in VGPRs; b double-buffered with a
// sched_barrier pinning the prefetch above the MFMA cluster.
// ---------------------------------------------------------------------------
__global__ __launch_bounds__(256, 2) void linear_mfma_duo(
        const unsigned short* __restrict__ xsA, const unsigned short* __restrict__ xmA,
        const unsigned short* __restrict__ BpA, const float* __restrict__ bsA,
        const float* __restrict__ bmA, const int* __restrict__ degA_, int nA,
        unsigned short* __restrict__ outA, int gmA,
        const unsigned short* __restrict__ xsP, const unsigned short* __restrict__ xmP,
        const unsigned short* __restrict__ BpP, const float* __restrict__ bsP,
        const float* __restrict__ bmP, const int* __restrict__ degP_, int nP,
        unsigned short* __restrict__ outP, int relu) {
    __shared__ uint4 lds4[4096];   // 64 KB: [128][256] bf16 swizzled
    unsigned char* lds = (unsigned char*)lds4;
    int tid = threadIdx.x;
    int wave = tid >> 6, lane = tid & 63;

    const unsigned short *xs, *xm, *Bpack; const float *bs, *bm;
    const int* deg; int n; unsigned short* out;
    int b = blockIdx.x;
    if (b < gmA) { xs = xsA; xm = xmA; Bpack = BpA; bs = bsA; bm = bmA;
                   deg = degA_; n = nA; out = outA; }
    else { b -= gmA; xs = xsP; xm = xmP; Bpack = BpP; bs = bsP; bm = bmP;
           deg = degP_; n = nP; out = outP; }
    int r_base = b * 128;

    // ---- stage [xs|xm] tile: 4096 16B chunks, 16 per thread ----
#pragma unroll
    for (int i = 0; i < 16; ++i) {
        int c = i * 256 + tid;        // 0..4095
        int row = c >> 5;             // 0..127
        int kc = (c & 31) * 8;        // bf16 elem offset 0..248
        int rg = r_base + row;
        uint4 w = make_uint4(0, 0, 0, 0);
        if (rg < n) {
            const unsigned short* src = (kc < D) ? (xs + (size_t)rg * D + kc)
                                                 : (xm + (size_t)rg * D + (kc - D));
            w = *(const uint4*)src;
        }
        unsigned addr = ((unsigned)(row * 512 + kc * 2)) ^ ((unsigned)((row & 7) << 4));
        *(uint4*)(lds + addr) = w;
    }
    __syncthreads();

    // ---- A fragments: 2 sub-tiles x 8 k-slices ----
    bf16x8_t a[2][8];
#pragma unroll
    for (int rt = 0; rt < 2; ++rt) {
        int lrow = wave * 32 + rt * 16 + (lane & 15);
#pragma unroll
        for (int ks = 0; ks < 8; ++ks) {
            unsigned addr = ((unsigned)(lrow * 512 + ks * 64 + (lane >> 4) * 16))
                            ^ ((unsigned)((lrow & 7) << 4));
            a[rt][ks] = *(const bf16x8_t*)(lds + addr);
        }
    }

    // ---- MFMA main loop with B register double-buffer ----
    f32x4_t acc[2][8];
#pragma unroll
    for (int rt = 0; rt < 2; ++rt)
#pragma unroll
        for (int nf = 0; nf < 8; ++nf) acc[rt][nf] = (f32x4_t){0.f, 0.f, 0.f, 0.f};

    const bf16x8_t* bp = (const bf16x8_t*)Bpack;
    bf16x8_t bcur[8], bnxt[8];
#pragma unroll
    for (int ks = 0; ks < 8; ++ks) bcur[ks] = bp[ks * 64 + lane];

#pragma unroll
    for (int nf = 0; nf < 8; ++nf) {
        if (nf < 7) {
#pragma unroll
            for (int ks = 0; ks < 8; ++ks)
                bnxt[ks] = bp[((nf + 1) * 8 + ks) * 64 + lane];
        }
        __builtin_amdgcn_sched_barrier(0);   // keep prefetch above the MFMAs
#pragma unroll
        for (int ks = 0; ks < 8; ++ks) {
            acc[0][nf] = __builtin_amdgcn_mfma_f32_16x16x32_bf16(a[0][ks], bcur[ks], acc[0][nf], 0, 0, 0);
            acc[1][nf] = __builtin_amdgcn_mfma_f32_16x16x32_bf16(a[1][ks], bcur[ks], acc[1][nf], 0, 0, 0);
        }
#pragma unroll
        for (int ks = 0; ks < 8; ++ks) bcur[ks] = bnxt[ks];
    }

    // ---- epilogue ----
#pragma unroll
    for (int rt = 0; rt < 2; ++rt) {
        int rb2 = r_base + wave * 32 + rt * 16 + (lane >> 4) * 4;
        float dg[4];
#pragma unroll
        for (int rr = 0; rr < 4; ++rr)
            dg[rr] = (rb2 + rr < n) ? (float)deg[rb2 + rr] : 0.f;

#pragma unroll
        for (int nf = 0; nf < 8; ++nf) {
            int col = nf * 16 + (lane & 15);
            float bsv = bs[col], bmv = bm[col];
#pragma unroll
            for (int rr = 0; rr < 4; ++rr) {
                int r = rb2 + rr;
                if (r < n) {
                    float v = acc[rt][nf][rr] + bsv + dg[rr] * bmv;
                    if (relu) v = fmaxf(v, 0.f);
                    out[(size_t)r * D + col] = f2bf(v);
                }
            }
        }
    }
}

// ---------------------------------------------------------------------------
// supervision dot products on bf16 embeddings
// ---------------------------------------------------------------------------
__global__ __launch_bounds__(256) void dot_kernel(
        const unsigned short* __restrict__ za, const unsigned short* __restrict__ zp,
        const int* __restrict__ sa, const int* __restrict__ sp, int S,
        float* __restrict__ out) {
    int gw   = (blockIdx.x * 256 + threadIdx.x) >> 6;
    int lane = threadIdx.x & 63;
    int nw   = (gridDim.x * 256) >> 6;
    for (int i = gw; i < S; i += nw) {
        int a = sa[i], p = sp[i];
        unsigned ua = *(const unsigned*)(za + (size_t)a * D + lane * 2);
        unsigned up = *(const unsigned*)(zp + (size_t)p * D + lane * 2);
        float s = bflo(ua) * bflo(up) + bfhi(ua) * bfhi(up);
#pragma unroll
        for (int off = 32; off > 0; off >>= 1) s += __shfl_xor(s, off);
        if (lane == 0) out[i] = s;
    }
}

// ---------------------------------------------------------------------------
extern "C" void kernel_launch(void* const* d_in, const int* in_sizes, int n_in,
                              void* d_out, int out_size, void* d_ws, size_t ws_size,
                              hipStream_t stream) {
    const float* x_a  = (const float*)d_in[0];
    const float* x_p  = (const float*)d_in[1];
    const int*   ea   = (const int*)d_in[2];
    const int*   ep   = (const int*)d_in[3];
    const int*   sa   = (const int*)d_in[4];
    const int*   sp   = (const int*)d_in[5];
    const float* WsA  = (const float*)d_in[6];
    const float* bsA  = (const float*)d_in[7];
    const float* WsP  = (const float*)d_in[8];
    const float* bsP  = (const float*)d_in[9];
    const float* Wa2p = (const float*)d_in[10];
    const float* ba2p = (const float*)d_in[11];
    const float* Wp2a = (const float*)d_in[12];
    const float* bp2a = (const float*)d_in[13];

    const int nA = in_sizes[0] / D;   // 100000
    const int nP = in_sizes[1] / D;   // 200000
    const int E  = in_sizes[2];       // 600000
    const int S  = in_sizes[4];       // 100000

    // ---- workspace layout ----
    char* ws = (char*)d_ws;
    size_t curoff = 0;
    auto alloc = [&](size_t bytes) -> void* {
        void* p = ws + curoff;
        curoff = (curoff + bytes + 255) & ~(size_t)255;
        return p;
    };
    unsigned short* xb_a  = (unsigned short*)alloc((size_t)nA * D * 2);
    unsigned short* xb_p  = (unsigned short*)alloc((size_t)nP * D * 2);
    unsigned short* agg_a = (unsigned short*)alloc((size_t)nA * D * 2);
    unsigned short* agg_p = (unsigned short*)alloc((size_t)nP * D * 2);
    unsigned short* y_a   = (unsigned short*)alloc((size_t)nA * D * 2);
    unsigned short* y_p   = (unsigned short*)alloc((size_t)nP * D * 2);
    unsigned short* z_a   = (unsigned short*)alloc((size_t)nA * D * 2);
    unsigned short* z_p   = (unsigned short*)alloc((size_t)nP * D * 2);
    int* degA = (int*)alloc((size_t)nA * 4);
    int* degP = (int*)alloc((size_t)nP * 4);
    int* rsA  = (int*)alloc(((size_t)nA + 1) * 4);
    int* rsP  = (int*)alloc(((size_t)nP + 1) * 4);
    int* csrA = (int*)alloc((size_t)E * 4);
    int* csrP = (int*)alloc((size_t)E * 4);
    const int gA = (nA + SCAN_TILE - 1) / SCAN_TILE;
    const int gP = (nP + SCAN_TILE - 1) / SCAN_TILE;
    int* partials = (int*)alloc((size_t)(gA + gP) * 4);
    unsigned short* Bpack = (unsigned short*)alloc((size_t)4 * 32768 * 2);  // 256 KB

    // multisplit structures alias z_a/z_p (preprocessing ends before layer 1)
    const int nbcA = (nA + CB_NODES - 1) >> CB_SHIFT;   // 49
    const int nbcP = (nP + CB_NODES - 1) >> CB_SHIFT;   // 98
    const int NBC  = nbcA + nbcP;                       // 147
    unsigned* buf = (unsigned*)z_a;           // 2E*4 = 4.8 MB
    int* gcur = (int*)z_p;                    // NBC ints

    // ---- bf16 input copies + graph preprocessing + W packing ----
    f32_to_bf16_duo<<<3072, 256, 0, stream>>>(x_a, xb_a, nA * D / 8,
                                              x_p, xb_p, nP * D / 8);
    size_t deg_bytes = (size_t)((char*)degP - (char*)degA) + (size_t)nP * 4;
    hipMemsetAsync(degA, 0, deg_bytes, stream);
    pack_w_kernel<<<64, 256, 0, stream>>>(WsA, WsP, Wa2p, Wp2a, Bpack);
    count_deg_kernel<<<1024, 256, 0, stream>>>(ea, ep, E, degA, degP);
    scan_partials_kernel<<<gA + gP, 256, 0, stream>>>(degA, nA, degP, nP, gA, partials);
    scan_block_sums_kernel<<<1, 1024, 0, stream>>>(partials, gA, gP, rsA + nA, rsP + nP);
    scan_write_kernel<<<gA + gP, 256, 0, stream>>>(degA, nA, rsA,
                                                   degP, nP, rsP, gA, partials);
    gcur_init_kernel<<<1, 256, 0, stream>>>(rsA, nbcA, rsP, NBC, E, gcur);
    multisplit_kernel<<<(E + CHE - 1) / CHE, 256, 0, stream>>>(ea, ep, E, nbcA, gcur, buf);
    fine_csr_kernel<<<NBC, 1024, 0, stream>>>(rsA, nA, nbcA, csrA,
                                              rsP, nP, csrP, buf, E);

    const int gmA = (nA + 127) / 128;   // 782
    const int gmP = (nP + 127) / 128;   // 1563
    const int gAgg = (nA + nP + 3) / 4;

    // ---- layer 0 (relu) ----
    aggregate_duo<<<gAgg, 256, 0, stream>>>(xb_p, rsA, csrA, nA, agg_a,
                                            xb_a, rsP, csrP, nP, agg_p);
    linear_mfma_duo<<<gmA + gmP, 256, 0, stream>>>(
        xb_a, agg_a, Bpack + 0 * 32768, bsA, bp2a, degA, nA, y_a, gmA,
        xb_p, agg_p, Bpack + 1 * 32768, bsP, ba2p, degP, nP, y_p, 1);

    // ---- layer 1 (no relu) ----
    aggregate_duo<<<gAgg, 256, 0, stream>>>(y_p, rsA, csrA, nA, agg_a,
                                            y_a, rsP, csrP, nP, agg_p);
    linear_mfma_duo<<<gmA + gmP, 256, 0, stream>>>(
        y_a, agg_a, Bpack + 2 * 32768, bsA + D, bp2a + D, degA, nA, z_a, gmA,
        y_p, agg_p, Bpack + 3 * 32768, bsP + D, ba2p + D, degP, nP, z_p, 0);

    // ---- supervision scores ----
    dot_kernel<<<(S + 3) / 4, 256, 0, stream>>>(z_a, z_p, sa, sp, S, (float*)d_out);
}

// Round 10
// 478.933 us; speedup vs baseline: 1.3147x; 1.0790x over previous
//
#include <hip/hip_runtime.h>
#include <stdint.h>

#define D 128
#define SCAN_TILE 1024  // elements per scan block (256 thr x 4)
#define CB_SHIFT 11     // coarse bucket = 2048 dst nodes
#define CB_NODES 2048
#define CHE 2048        // edges per multisplit chunk (2*CHE entries)

typedef __attribute__((ext_vector_type(8))) short bf16x8_t;
typedef __attribute__((ext_vector_type(4))) float f32x4_t;

__device__ inline unsigned short f2bf(float x) {
    unsigned int u = __float_as_uint(x);
    unsigned int r = (u + 0x7fffu + ((u >> 16) & 1u)) >> 16;   // RNE
    return (unsigned short)r;
}
__device__ inline float bflo(unsigned v) { return __uint_as_float(v << 16); }
__device__ inline float bfhi(unsigned v) { return __uint_as_float(v & 0xffff0000u); }

// ---------------------------------------------------------------------------
// f32 -> bf16 bulk convert, both arrays in one launch
// ---------------------------------------------------------------------------
__global__ __launch_bounds__(256) void f32_to_bf16_duo(
        const float* __restrict__ inA, unsigned short* __restrict__ outA, int n8A,
        const float* __restrict__ inP, unsigned short* __restrict__ outP, int n8P) {
    int stride = gridDim.x * blockDim.x;
    int total = n8A + n8P;
    for (int i = blockIdx.x * blockDim.x + threadIdx.x; i < total; i += stride) {
        const float* in; unsigned short* out; int j;
        if (i < n8A) { in = inA; out = outA; j = i; }
        else         { in = inP; out = outP; j = i - n8A; }
        float4 v0 = *(const float4*)(in + (size_t)j * 8);
        float4 v1 = *(const float4*)(in + (size_t)j * 8 + 4);
        uint4 o;
        o.x = f2bf(v0.x) | ((unsigned)f2bf(v0.y) << 16);
        o.y = f2bf(v0.z) | ((unsigned)f2bf(v0.w) << 16);
        o.z = f2bf(v1.x) | ((unsigned)f2bf(v1.y) << 16);
        o.w = f2bf(v1.z) | ((unsigned)f2bf(v1.w) << 16);
        *(uint4*)(out + (size_t)j * 8) = o;
    }
}

// ---------------------------------------------------------------------------
// deg histogram
// ---------------------------------------------------------------------------
__global__ void count_deg_kernel(const int* __restrict__ ea, const int* __restrict__ ep,
                                 int E, int* __restrict__ degA, int* __restrict__ degP) {
    int stride = gridDim.x * blockDim.x;
    for (int e = blockIdx.x * blockDim.x + threadIdx.x; e < E; e += stride) {
        atomicAdd(&degA[ea[e]], 1);
        atomicAdd(&degP[ep[e]], 1);
    }
}

// ---------------------------------------------------------------------------
// 3-pass device-wide exclusive scan over BOTH deg arrays
// ---------------------------------------------------------------------------
__global__ __launch_bounds__(256) void scan_partials_kernel(
        const int* __restrict__ degA, int nA,
        const int* __restrict__ degP, int nP, int gA,
        int* __restrict__ partials) {
    const int* deg; int n;
    int b = blockIdx.x;
    if (b < gA) { deg = degA; n = nA; }
    else        { deg = degP; n = nP; b -= gA; }
    int tid = threadIdx.x;
    int i0 = b * SCAN_TILE + tid * 4;
    int s = 0;
    if (i0 + 3 < n) {
        int4 d = *(const int4*)(deg + i0);
        s = d.x + d.y + d.z + d.w;
    } else {
        for (int j = 0; j < 4; ++j) if (i0 + j < n) s += deg[i0 + j];
    }
#pragma unroll
    for (int off = 32; off; off >>= 1) s += __shfl_xor(s, off);
    __shared__ int wsum[4];
    if ((tid & 63) == 0) wsum[tid >> 6] = s;
    __syncthreads();
    if (tid == 0) partials[blockIdx.x] = wsum[0] + wsum[1] + wsum[2] + wsum[3];
}

__global__ __launch_bounds__(1024) void scan_block_sums_kernel(
        int* __restrict__ partials, int gA, int gP,
        int* __restrict__ rsA_end, int* __restrict__ rsP_end) {
    __shared__ int s[1024];
    int n = gA + gP;
    int tid = threadIdx.x;
    int v = (tid < n) ? partials[tid] : 0;
    s[tid] = v;
    __syncthreads();
    for (int off = 1; off < 1024; off <<= 1) {
        int add = 0;
        if (tid >= off && ((tid < gA) || (tid - off >= gA))) add = s[tid - off];
        __syncthreads();
        s[tid] += add;
        __syncthreads();
    }
    if (tid == gA - 1)  *rsA_end = s[tid];
    if (tid == n - 1)   *rsP_end = s[tid];
    if (tid < n) partials[tid] = s[tid] - v;
}

__global__ __launch_bounds__(256) void scan_write_kernel(
        const int* __restrict__ degA, int nA, int* __restrict__ rsA,
        const int* __restrict__ degP, int nP, int* __restrict__ rsP,
        int gA, const int* __restrict__ partials) {
    const int* deg; int n; int* rs;
    int b = blockIdx.x;
    int part = partials[blockIdx.x];
    if (b < gA) { deg = degA; n = nA; rs = rsA; }
    else        { deg = degP; n = nP; rs = rsP; b -= gA; }
    int tid = threadIdx.x;
    int lane = tid & 63, wid = tid >> 6;
    int i0 = b * SCAN_TILE + tid * 4;

    int4 d = make_int4(0, 0, 0, 0);
    if (i0 + 3 < n) {
        d = *(const int4*)(deg + i0);
    } else {
        if (i0 + 0 < n) d.x = deg[i0 + 0];
        if (i0 + 1 < n) d.y = deg[i0 + 1];
        if (i0 + 2 < n) d.z = deg[i0 + 2];
        if (i0 + 3 < n) d.w = deg[i0 + 3];
    }
    int tsum = d.x + d.y + d.z + d.w;

    int x = tsum;
#pragma unroll
    for (int off = 1; off < 64; off <<= 1) {
        int y = __shfl_up(x, off);
        if (lane >= off) x += y;
    }
    int excl = x - tsum;

    __shared__ int wsum[4];
    if (lane == 63) wsum[wid] = x;
    __syncthreads();
    int woff = 0;
#pragma unroll
    for (int w = 0; w < 4; ++w) if (w < wid) woff += wsum[w];

    int off0 = part + woff + excl;
    int4 o;
    o.x = off0;
    o.y = off0 + d.x;
    o.z = o.y + d.y;
    o.w = o.z + d.z;
    if (i0 + 3 < n) {
        *(int4*)(rs + i0) = o;
    } else {
        if (i0 + 0 < n) rs[i0 + 0] = o.x;
        if (i0 + 1 < n) rs[i0 + 1] = o.y;
        if (i0 + 2 < n) rs[i0 + 2] = o.z;
        if (i0 + 3 < n) rs[i0 + 3] = o.w;
    }
}

// ---------------------------------------------------------------------------
// coarse cursor init
// ---------------------------------------------------------------------------
__global__ __launch_bounds__(256) void gcur_init_kernel(
        const int* __restrict__ rsA, int nbcA,
        const int* __restrict__ rsP, int nbc, int E, int* __restrict__ gcur) {
    int i = blockIdx.x * blockDim.x + threadIdx.x;
    if (i < nbcA)                gcur[i] = rsA[i << CB_SHIFT];
    else if (i < nbc)            gcur[i] = E + rsP[(i - nbcA) << CB_SHIFT];
}

// ---------------------------------------------------------------------------
// LDS multisplit (block-owned contiguous runs per coarse bucket)
// ---------------------------------------------------------------------------
__global__ __launch_bounds__(256) void multisplit_kernel(
        const int* __restrict__ ea, const int* __restrict__ ep, int E,
        int nbcA, int* __restrict__ gcur, unsigned* __restrict__ buf) {
    __shared__ int hist[256];
    __shared__ int off[256];
    __shared__ int cnt2[256];
    __shared__ int gbase[256];
    __shared__ unsigned cbuf[2 * CHE];
    __shared__ unsigned char bkt[2 * CHE];

    int tid = threadIdx.x;
    int e0 = blockIdx.x * CHE;
    int ecnt = E - e0; if (ecnt > CHE) ecnt = CHE;

    hist[tid] = 0;
    __syncthreads();

    for (int k = tid; k < ecnt; k += 256) {
        int a = ea[e0 + k], p = ep[e0 + k];
        atomicAdd(&hist[a >> CB_SHIFT], 1);
        atomicAdd(&hist[nbcA + (p >> CB_SHIFT)], 1);
    }
    __syncthreads();

    int v = hist[tid];
    off[tid] = v;
    __syncthreads();
    for (int o = 1; o < 256; o <<= 1) {
        int y = (tid >= o) ? off[tid - o] : 0;
        __syncthreads();
        off[tid] += y;
        __syncthreads();
    }
    int excl = off[tid] - v;
    off[tid] = excl;
    cnt2[tid] = 0;
    if (v > 0) gbase[tid] = atomicAdd(&gcur[tid], v);
    __syncthreads();

    for (int k = tid; k < ecnt; k += 256) {
        int a = ea[e0 + k], p = ep[e0 + k];
        int bA = a >> CB_SHIFT;
        int iA = off[bA] + atomicAdd(&cnt2[bA], 1);
        cbuf[iA] = ((unsigned)p << CB_SHIFT) | (unsigned)(a & (CB_NODES - 1));
        bkt[iA] = (unsigned char)bA;
        int bP = nbcA + (p >> CB_SHIFT);
        int iP = off[bP] + atomicAdd(&cnt2[bP], 1);
        cbuf[iP] = ((unsigned)a << CB_SHIFT) | (unsigned)(p & (CB_NODES - 1));
        bkt[iP] = (unsigned char)bP;
    }
    __syncthreads();

    int total = 2 * ecnt;
    for (int i = tid; i < total; i += 256) {
        int b = bkt[i];
        buf[(size_t)gbase[b] + (i - off[b])] = cbuf[i];
    }
}

// ---------------------------------------------------------------------------
// fine sort: one block per coarse bucket
// ---------------------------------------------------------------------------
__global__ __launch_bounds__(1024) void fine_csr_kernel(
        const int* __restrict__ rsA, int nA, int nbcA, int* __restrict__ csrA,
        const int* __restrict__ rsP, int nP, int* __restrict__ csrP,
        const unsigned* __restrict__ buf, int E) {
    __shared__ int base[CB_NODES + 1];
    __shared__ int cnt[CB_NODES];
    const int* rs; int* csr; int n; int d0; const unsigned* mybuf;
    int b = blockIdx.x;
    if (b < nbcA) { rs = rsA; csr = csrA; n = nA; d0 = b << CB_SHIFT; mybuf = buf; }
    else { rs = rsP; csr = csrP; n = nP; d0 = (b - nbcA) << CB_SHIFT; mybuf = buf + E; }
    int nd = n - d0; if (nd > CB_NODES) nd = CB_NODES;

    int tid = threadIdx.x;
    for (int i = tid; i <= nd; i += 1024) base[i] = rs[d0 + i];
    for (int i = tid; i < nd; i += 1024) cnt[i] = 0;
    __syncthreads();

    int g0 = base[0], g1 = base[nd];
    for (int j = g0 + tid; j < g1; j += 1024) {
        unsigned pk = mybuf[j];
        int li = pk & (CB_NODES - 1);
        int src = (int)(pk >> CB_SHIFT);
        int pos = base[li] + atomicAdd(&cnt[li], 1);
        csr[pos] = src;
    }
}

// ---------------------------------------------------------------------------
// W pre-pack (unchanged)
// ---------------------------------------------------------------------------
__global__ __launch_bounds__(256) void pack_w_kernel(
        const float* __restrict__ WsA, const float* __restrict__ WsP,
        const float* __restrict__ Wa2p, const float* __restrict__ Wp2a,
        unsigned short* __restrict__ Bpack) {
    int combo = blockIdx.x >> 4;
    int e = (blockIdx.x & 15) * 256 + threadIdx.x;   // 0..4095
    int layer = combo >> 1;
    const float* Ws = ((combo & 1) ? WsP : WsA) + (size_t)layer * D * D;
    const float* Wm = ((combo & 1) ? Wa2p : Wp2a) + (size_t)layer * D * D;

    int f = e >> 6, lane = e & 63;
    int nf = f >> 3, ks = f & 7;
    int k0 = ks * 32 + (lane >> 4) * 8;
    int col = nf * 16 + (lane & 15);

    unsigned short v[8];
#pragma unroll
    for (int j = 0; j < 8; ++j) {
        int k = k0 + j;
        float x = (k < D) ? Ws[(size_t)k * D + col] : Wm[(size_t)(k - D) * D + col];
        v[j] = f2bf(x);
    }
    uint4 o;
    o.x = v[0] | ((unsigned)v[1] << 16);
    o.y = v[2] | ((unsigned)v[3] << 16);
    o.z = v[4] | ((unsigned)v[5] << 16);
    o.w = v[6] | ((unsigned)v[7] << 16);
    *(uint4*)(Bpack + (size_t)combo * 32768 + (size_t)e * 8) = o;
}

// ---------------------------------------------------------------------------
// bf16 pull-aggregation, BOTH directions in one launch.
// ---------------------------------------------------------------------------
__global__ __launch_bounds__(256) void aggregate_duo(
        const unsigned short* __restrict__ srcA, const int* __restrict__ rsA,
        const int* __restrict__ csrA, int nA, unsigned short* __restrict__ aggA,
        const unsigned short* __restrict__ srcP, const int* __restrict__ rsP,
        const int* __restrict__ csrP, int nP, unsigned short* __restrict__ aggP) {
    int gw   = (blockIdx.x * 256 + threadIdx.x) >> 6;
    int lane = threadIdx.x & 63;
    int sub  = lane >> 4;
    int sl   = lane & 15;

    const unsigned short* xsrc; const int* rs; const int* csr;
    unsigned short* agg; int d;
    if (gw < nA) { d = gw;      xsrc = srcA; rs = rsA; csr = csrA; agg = aggA; }
    else {
        d = gw - nA;
        if (d >= nP) return;
        xsrc = srcP; rs = rsP; csr = csrP; agg = aggP;
    }

    int s0 = rs[d], s1 = rs[d + 1];
    float acc[8] = {0.f, 0.f, 0.f, 0.f, 0.f, 0.f, 0.f, 0.f};
    for (int j = s0 + sub; j < s1; j += 4) {
        int s = csr[j];
        uint4 v = *(const uint4*)(xsrc + (size_t)s * D + sl * 8);
        acc[0] += bflo(v.x); acc[1] += bfhi(v.x);
        acc[2] += bflo(v.y); acc[3] += bfhi(v.y);
        acc[4] += bflo(v.z); acc[5] += bfhi(v.z);
        acc[6] += bflo(v.w); acc[7] += bfhi(v.w);
    }
#pragma unroll
    for (int i = 0; i < 8; ++i) {
        acc[i] += __shfl_xor(acc[i], 16);
        acc[i] += __shfl_xor(acc[i], 32);
    }
    if (sub == 0) {
        uint4 o;
        o.x = f2bf(acc[0]) | ((unsigned)f2bf(acc[1]) << 16);
        o.y = f2bf(acc[2]) | ((unsigned)f2bf(acc[3]) << 16);
        o.z = f2bf(acc[4]) | ((unsigned)f2bf(acc[5]) << 16);
        o.w = f2bf(acc[6]) | ((unsigned)f2bf(acc[7]) << 16);
        *(uint4*)(agg + (size_t)d * D + sl * 8) = o;
    }
}

// ---------------------------------------------------------------------------
// MFMA node update, column-split: block = 64 rows x 128 cols, 4 waves.
// Wave w owns cols [32w,32w+32): its 16KB B slice is loaded ONCE per block
// into registers (b[2][8]) and stays L1-resident across blocks -> the
// round-8/9 per-nf B-latency stall disappears. Waves iterate the 4 row
// sub-tiles via LDS (same addresses across waves = free broadcast).
// ---------------------------------------------------------------------------
__global__ __launch_bounds__(256) void linear_mfma_duo(
        const unsigned short* __restrict__ xsA, const unsigned short* __restrict__ xmA,
        const unsigned short* __restrict__ BpA, const float* __restrict__ bsA,
        const float* __restrict__ bmA, const int* __restrict__ degA_, int nA,
        unsigned short* __restrict__ outA, int gmA,
        const unsigned short* __restrict__ xsP, const unsigned short* __restrict__ xmP,
        const unsigned short* __restrict__ BpP, const float* __restrict__ bsP,
        const float* __restrict__ bmP, const int* __restrict__ degP_, int nP,
        unsigned short* __restrict__ outP, int relu) {
    __shared__ uint4 lds4[2048];   // 32 KB: [64][256] bf16 swizzled
    unsigned char* lds = (unsigned char*)lds4;
    int tid = threadIdx.x;
    int wave = tid >> 6, lane = tid & 63;

    const unsigned short *xs, *xm, *Bpack; const float *bs, *bm;
    const int* deg; int n; unsigned short* out;
    int b = blockIdx.x;
    if (b < gmA) { xs = xsA; xm = xmA; Bpack = BpA; bs = bsA; bm = bmA;
                   deg = degA_; n = nA; out = outA; }
    else { b -= gmA; xs = xsP; xm = xmP; Bpack = BpP; bs = bsP; bm = bmP;
           deg = degP_; n = nP; out = outP; }
    int r_base = b * 64;

    // ---- load this wave's B slice (cols 32w..32w+31): 16 fragments, once ----
    const bf16x8_t* bp = (const bf16x8_t*)Bpack;
    bf16x8_t bb[2][8];
#pragma unroll
    for (int nf2 = 0; nf2 < 2; ++nf2)
#pragma unroll
        for (int ks = 0; ks < 8; ++ks)
            bb[nf2][ks] = bp[((wave * 2 + nf2) * 8 + ks) * 64 + lane];

    // ---- stage [xs|xm] tile: 2048 16B chunks, 8 per thread ----
#pragma unroll
    for (int i = 0; i < 8; ++i) {
        int c = i * 256 + tid;        // 0..2047
        int row = c >> 5;             // 0..63
        int kc = (c & 31) * 8;        // bf16 elem offset 0..248
        int rg = r_base + row;
        uint4 w = make_uint4(0, 0, 0, 0);
        if (rg < n) {
            const unsigned short* src = (kc < D) ? (xs + (size_t)rg * D + kc)
                                                 : (xm + (size_t)rg * D + (kc - D));
            w = *(const uint4*)src;
        }
        unsigned addr = ((unsigned)(row * 512 + kc * 2)) ^ ((unsigned)((row & 7) << 4));
        *(uint4*)(lds + addr) = w;
    }
    __syncthreads();

    // ---- row sub-tile loop: a from LDS, 16 MFMAs per rt ----
    f32x4_t acc[4][2];
#pragma unroll
    for (int rt = 0; rt < 4; ++rt)
#pragma unroll
        for (int nf2 = 0; nf2 < 2; ++nf2) acc[rt][nf2] = (f32x4_t){0.f, 0.f, 0.f, 0.f};

#pragma unroll
    for (int rt = 0; rt < 4; ++rt) {
        int lrow = rt * 16 + (lane & 15);
        bf16x8_t a[8];
#pragma unroll
        for (int ks = 0; ks < 8; ++ks) {
            unsigned addr = ((unsigned)(lrow * 512 + ks * 64 + (lane >> 4) * 16))
                            ^ ((unsigned)((lrow & 7) << 4));
            a[ks] = *(const bf16x8_t*)(lds + addr);
        }
#pragma unroll
        for (int ks = 0; ks < 8; ++ks) {
            acc[rt][0] = __builtin_amdgcn_mfma_f32_16x16x32_bf16(a[ks], bb[0][ks], acc[rt][0], 0, 0, 0);
            acc[rt][1] = __builtin_amdgcn_mfma_f32_16x16x32_bf16(a[ks], bb[1][ks], acc[rt][1], 0, 0, 0);
        }
    }

    // ---- epilogue: wave w writes cols [32w,32w+32) for all 64 rows ----
#pragma unroll
    for (int nf2 = 0; nf2 < 2; ++nf2) {
        int col = wave * 32 + nf2 * 16 + (lane & 15);
        float bsv = bs[col], bmv = bm[col];
#pragma unroll
        for (int rt = 0; rt < 4; ++rt) {
            int rb2 = r_base + rt * 16 + (lane >> 4) * 4;
#pragma unroll
            for (int rr = 0; rr < 4; ++rr) {
                int r = rb2 + rr;
                if (r < n) {
                    float dgv = (float)deg[r];
                    float v = acc[rt][nf2][rr] + bsv + dgv * bmv;
                    if (relu) v = fmaxf(v, 0.f);
                    out[(size_t)r * D + col] = f2bf(v);
                }
            }
        }
    }
}

// ---------------------------------------------------------------------------
// supervision dot products on bf16 embeddings
// ---------------------------------------------------------------------------
__global__ __launch_bounds__(256) void dot_kernel(
        const unsigned short* __restrict__ za, const unsigned short* __restrict__ zp,
        const int* __restrict__ sa, const int* __restrict__ sp, int S,
        float* __restrict__ out) {
    int gw   = (blockIdx.x * 256 + threadIdx.x) >> 6;
    int lane = threadIdx.x & 63;
    int nw   = (gridDim.x * 256) >> 6;
    for (int i = gw; i < S; i += nw) {
        int a = sa[i], p = sp[i];
        unsigned ua = *(const unsigned*)(za + (size_t)a * D + lane * 2);
        unsigned up = *(const unsigned*)(zp + (size_t)p * D + lane * 2);
        float s = bflo(ua) * bflo(up) + bfhi(ua) * bfhi(up);
#pragma unroll
        for (int off = 32; off > 0; off >>= 1) s += __shfl_xor(s, off);
        if (lane == 0) out[i] = s;
    }
}

// ---------------------------------------------------------------------------
extern "C" void kernel_launch(void* const* d_in, const int* in_sizes, int n_in,
                              void* d_out, int out_size, void* d_ws, size_t ws_size,
                              hipStream_t stream) {
    const float* x_a  = (const float*)d_in[0];
    const float* x_p  = (const float*)d_in[1];
    const int*   ea   = (const int*)d_in[2];
    const int*   ep   = (const int*)d_in[3];
    const int*   sa   = (const int*)d_in[4];
    const int*   sp   = (const int*)d_in[5];
    const float* WsA  = (const float*)d_in[6];
    const float* bsA  = (const float*)d_in[7];
    const float* WsP  = (const float*)d_in[8];
    const float* bsP  = (const float*)d_in[9];
    const float* Wa2p = (const float*)d_in[10];
    const float* ba2p = (const float*)d_in[11];
    const float* Wp2a = (const float*)d_in[12];
    const float* bp2a = (const float*)d_in[13];

    const int nA = in_sizes[0] / D;   // 100000
    const int nP = in_sizes[1] / D;   // 200000
    const int E  = in_sizes[2];       // 600000
    const int S  = in_sizes[4];       // 100000

    // ---- workspace layout ----
    char* ws = (char*)d_ws;
    size_t curoff = 0;
    auto alloc = [&](size_t bytes) -> void* {
        void* p = ws + curoff;
        curoff = (curoff + bytes + 255) & ~(size_t)255;
        return p;
    };
    unsigned short* xb_a  = (unsigned short*)alloc((size_t)nA * D * 2);
    unsigned short* xb_p  = (unsigned short*)alloc((size_t)nP * D * 2);
    unsigned short* agg_a = (unsigned short*)alloc((size_t)nA * D * 2);
    unsigned short* agg_p = (unsigned short*)alloc((size_t)nP * D * 2);
    unsigned short* y_a   = (unsigned short*)alloc((size_t)nA * D * 2);
    unsigned short* y_p   = (unsigned short*)alloc((size_t)nP * D * 2);
    unsigned short* z_a   = (unsigned short*)alloc((size_t)nA * D * 2);
    unsigned short* z_p   = (unsigned short*)alloc((size_t)nP * D * 2);
    int* degA = (int*)alloc((size_t)nA * 4);
    int* degP = (int*)alloc((size_t)nP * 4);
    int* rsA  = (int*)alloc(((size_t)nA + 1) * 4);
    int* rsP  = (int*)alloc(((size_t)nP + 1) * 4);
    int* csrA = (int*)alloc((size_t)E * 4);
    int* csrP = (int*)alloc((size_t)E * 4);
    const int gA = (nA + SCAN_TILE - 1) / SCAN_TILE;
    const int gP = (nP + SCAN_TILE - 1) / SCAN_TILE;
    int* partials = (int*)alloc((size_t)(gA + gP) * 4);
    unsigned short* Bpack = (unsigned short*)alloc((size_t)4 * 32768 * 2);  // 256 KB

    // multisplit structures alias z_a/z_p (preprocessing ends before layer 1)
    const int nbcA = (nA + CB_NODES - 1) >> CB_SHIFT;   // 49
    const int nbcP = (nP + CB_NODES - 1) >> CB_SHIFT;   // 98
    const int NBC  = nbcA + nbcP;                       // 147
    unsigned* buf = (unsigned*)z_a;           // 2E*4 = 4.8 MB
    int* gcur = (int*)z_p;                    // NBC ints

    // ---- bf16 input copies + graph preprocessing + W packing ----
    f32_to_bf16_duo<<<3072, 256, 0, stream>>>(x_a, xb_a, nA * D / 8,
                                              x_p, xb_p, nP * D / 8);
    size_t deg_bytes = (size_t)((char*)degP - (char*)degA) + (size_t)nP * 4;
    hipMemsetAsync(degA, 0, deg_bytes, stream);
    pack_w_kernel<<<64, 256, 0, stream>>>(WsA, WsP, Wa2p, Wp2a, Bpack);
    count_deg_kernel<<<1024, 256, 0, stream>>>(ea, ep, E, degA, degP);
    scan_partials_kernel<<<gA + gP, 256, 0, stream>>>(degA, nA, degP, nP, gA, partials);
    scan_block_sums_kernel<<<1, 1024, 0, stream>>>(partials, gA, gP, rsA + nA, rsP + nP);
    scan_write_kernel<<<gA + gP, 256, 0, stream>>>(degA, nA, rsA,
                                                   degP, nP, rsP, gA, partials);
    gcur_init_kernel<<<1, 256, 0, stream>>>(rsA, nbcA, rsP, NBC, E, gcur);
    multisplit_kernel<<<(E + CHE - 1) / CHE, 256, 0, stream>>>(ea, ep, E, nbcA, gcur, buf);
    fine_csr_kernel<<<NBC, 1024, 0, stream>>>(rsA, nA, nbcA, csrA,
                                              rsP, nP, csrP, buf, E);

    const int gmA = (nA + 63) / 64;   // 1563
    const int gmP = (nP + 63) / 64;   // 3125
    const int gAgg = (nA + nP + 3) / 4;

    // ---- layer 0 (relu) ----
    aggregate_duo<<<gAgg, 256, 0, stream>>>(xb_p, rsA, csrA, nA, agg_a,
                                            xb_a, rsP, csrP, nP, agg_p);
    linear_mfma_duo<<<gmA + gmP, 256, 0, stream>>>(
        xb_a, agg_a, Bpack + 0 * 32768, bsA, bp2a, degA, nA, y_a, gmA,
        xb_p, agg_p, Bpack + 1 * 32768, bsP, ba2p, degP, nP, y_p, 1);

    // ---- layer 1 (no relu) ----
    aggregate_duo<<<gAgg, 256, 0, stream>>>(y_p, rsA, csrA, nA, agg_a,
                                            y_a, rsP, csrP, nP, agg_p);
    linear_mfma_duo<<<gmA + gmP, 256, 0, stream>>>(
        y_a, agg_a, Bpack + 2 * 32768, bsA + D, bp2a + D, degA, nA, z_a, gmA,
        y_p, agg_p, Bpack + 3 * 32768, bsP + D, ba2p + D, degP, nP, z_p, 0);

    // ---- supervision scores ----
    dot_kernel<<<(S + 3) / 4, 256, 0, stream>>>(z_a, z_p, sa, sp, S, (float*)d_out);
}

// Round 11
// 431.954 us; speedup vs baseline: 1.4577x; 1.1088x over previous
//
#include <hip/hip_runtime.h>
#include <stdint.h>

#define D 128
#define CB_SHIFT 10     // coarse bucket = 1024 dst nodes
#define CB_NODES 1024
#define CHE 2048        // edges per multisplit chunk (2*CHE entries)
#define NBC_MAX 512

typedef __attribute__((ext_vector_type(8))) short bf16x8_t;
typedef __attribute__((ext_vector_type(4))) float f32x4_t;

__device__ inline unsigned short f2bf(float x) {
    unsigned int u = __float_as_uint(x);
    unsigned int r = (u + 0x7fffu + ((u >> 16) & 1u)) >> 16;   // RNE
    return (unsigned short)r;
}
__device__ inline float bflo(unsigned v) { return __uint_as_float(v << 16); }

// ---------------------------------------------------------------------------
// f32 -> bf16 bulk convert, both arrays in one launch
// ---------------------------------------------------------------------------
__global__ __launch_bounds__(256) void f32_to_bf16_duo(
        const float* __restrict__ inA, unsigned short* __restrict__ outA, int n8A,
        const float* __restrict__ inP, unsigned short* __restrict__ outP, int n8P) {
    int stride = gridDim.x * blockDim.x;
    int total = n8A + n8P;
    for (int i = blockIdx.x * blockDim.x + threadIdx.x; i < total; i += stride) {
        const float* in; unsigned short* out; int j;
        if (i < n8A) { in = inA; out = outA; j = i; }
        else         { in = inP; out = outP; j = i - n8A; }
        float4 v0 = *(const float4*)(in + (size_t)j * 8);
        float4 v1 = *(const float4*)(in + (size_t)j * 8 + 4);
        uint4 o;
        o.x = f2bf(v0.x) | ((unsigned)f2bf(v0.y) << 16);
        o.y = f2bf(v0.z) | ((unsigned)f2bf(v0.w) << 16);
        o.z = f2bf(v1.x) | ((unsigned)f2bf(v1.y) << 16);
        o.w = f2bf(v1.z) | ((unsigned)f2bf(v1.w) << 16);
        *(uint4*)(out + (size_t)j * 8) = o;
    }
}

// ---------------------------------------------------------------------------
// coarse bucket histogram: LDS per-block hist -> one global atomic per
// (block,bucket). Replaces per-node count_deg (1.2M random atomics).
// ---------------------------------------------------------------------------
__global__ __launch_bounds__(256) void coarse_count_kernel(
        const int* __restrict__ ea, const int* __restrict__ ep, int E,
        int nbcA, int nbc, int* __restrict__ chist) {
    __shared__ int hist[NBC_MAX];
    int tid = threadIdx.x;
    for (int i = tid; i < NBC_MAX; i += 256) hist[i] = 0;
    __syncthreads();
    int e0 = blockIdx.x * CHE;
    int ecnt = E - e0; if (ecnt > CHE) ecnt = CHE;
    for (int k = tid; k < ecnt; k += 256) {
        int a = ea[e0 + k], p = ep[e0 + k];
        atomicAdd(&hist[a >> CB_SHIFT], 1);
        atomicAdd(&hist[nbcA + (p >> CB_SHIFT)], 1);
    }
    __syncthreads();
    for (int i = tid; i < nbc; i += 256)
        if (hist[i]) atomicAdd(&chist[i], hist[i]);
}

// ---------------------------------------------------------------------------
// tiny segmented scan of the 294 coarse counts (1 block). Writes per-bucket
// csr-space bases (cbase), multisplit cursors (gcur), and the rs[] tails.
// ---------------------------------------------------------------------------
__global__ __launch_bounds__(NBC_MAX) void coarse_scan_kernel(
        const int* __restrict__ chist, int nbcA, int nbc, int E,
        int* __restrict__ gcur, int* __restrict__ cbase,
        int* __restrict__ rsA_end, int* __restrict__ rsP_end) {
    __shared__ int s[NBC_MAX];
    int tid = threadIdx.x;
    int v = (tid < nbc) ? chist[tid] : 0;
    s[tid] = v;
    __syncthreads();
    for (int off = 1; off < NBC_MAX; off <<= 1) {
        int add = 0;
        if (tid >= off && ((tid < nbcA) || (tid - off >= nbcA))) add = s[tid - off];
        __syncthreads();
        s[tid] += add;
        __syncthreads();
    }
    int excl = s[tid] - v;
    if (tid < nbc) {
        cbase[tid] = excl;
        gcur[tid] = (tid < nbcA) ? excl : E + excl;
    }
    if (tid == 0) { *rsA_end = E; *rsP_end = E; }
}

// ---------------------------------------------------------------------------
// LDS multisplit (block-owned contiguous runs per coarse bucket), 512 thr
// ---------------------------------------------------------------------------
__global__ __launch_bounds__(512) void multisplit_kernel(
        const int* __restrict__ ea, const int* __restrict__ ep, int E,
        int nbcA, int* __restrict__ gcur, unsigned* __restrict__ buf) {
    __shared__ int hist[NBC_MAX];
    __shared__ int off[NBC_MAX];
    __shared__ int cnt2[NBC_MAX];
    __shared__ int gbase[NBC_MAX];
    __shared__ unsigned cbuf[2 * CHE];          // 16 KB
    __shared__ unsigned short bkt[2 * CHE];     // 8 KB

    int tid = threadIdx.x;
    int e0 = blockIdx.x * CHE;
    int ecnt = E - e0; if (ecnt > CHE) ecnt = CHE;

    hist[tid] = 0;
    __syncthreads();

    for (int k = tid; k < ecnt; k += 512) {
        int a = ea[e0 + k], p = ep[e0 + k];
        atomicAdd(&hist[a >> CB_SHIFT], 1);
        atomicAdd(&hist[nbcA + (p >> CB_SHIFT)], 1);
    }
    __syncthreads();

    int v = hist[tid];
    off[tid] = v;
    __syncthreads();
    for (int o = 1; o < NBC_MAX; o <<= 1) {
        int y = (tid >= o) ? off[tid - o] : 0;
        __syncthreads();
        off[tid] += y;
        __syncthreads();
    }
    int excl = off[tid] - v;
    off[tid] = excl;
    cnt2[tid] = 0;
    if (v > 0) gbase[tid] = atomicAdd(&gcur[tid], v);
    __syncthreads();

    for (int k = tid; k < ecnt; k += 512) {
        int a = ea[e0 + k], p = ep[e0 + k];
        int bA = a >> CB_SHIFT;
        int iA = off[bA] + atomicAdd(&cnt2[bA], 1);
        cbuf[iA] = ((unsigned)p << CB_SHIFT) | (unsigned)(a & (CB_NODES - 1));
        bkt[iA] = (unsigned short)bA;
        int bP = nbcA + (p >> CB_SHIFT);
        int iP = off[bP] + atomicAdd(&cnt2[bP], 1);
        cbuf[iP] = ((unsigned)a << CB_SHIFT) | (unsigned)(p & (CB_NODES - 1));
        bkt[iP] = (unsigned short)bP;
    }
    __syncthreads();

    int total = 2 * ecnt;
    for (int i = tid; i < total; i += 512) {
        int b = bkt[i];
        buf[(size_t)gbase[b] + (i - off[b])] = cbuf[i];
    }
}

// ---------------------------------------------------------------------------
// fine sort + LOCAL deg/rs derivation: one block per coarse bucket.
// Pass 1: LDS histogram of the bucket's entries -> block scan -> write
// rs[] and deg[] (replaces the old device-wide per-node scan entirely).
// Pass 2: scatter src into the bucket's contiguous csr region.
// ---------------------------------------------------------------------------
__global__ __launch_bounds__(1024) void fine_csr_kernel(
        const unsigned* __restrict__ buf, int E, int nbcA,
        const int* __restrict__ cbase, const int* __restrict__ chist,
        int* __restrict__ rsA, int* __restrict__ degA, int* __restrict__ csrA, int nA,
        int* __restrict__ rsP, int* __restrict__ degP, int* __restrict__ csrP, int nP) {
    __shared__ int cnt[CB_NODES];
    __shared__ int s[CB_NODES];
    __shared__ int pos[CB_NODES];
    int b = blockIdx.x;
    int tid = threadIdx.x;
    int isA = (b < nbcA);
    int d0 = (isA ? b : b - nbcA) << CB_SHIFT;
    int n  = isA ? nA : nP;
    int* rs  = isA ? rsA  : rsP;
    int* deg = isA ? degA : degP;
    int* csr = isA ? csrA : csrP;
    int cb   = cbase[b];
    int cntE = chist[b];
    size_t bstart = (isA ? (size_t)0 : (size_t)E) + (size_t)cb;

    cnt[tid] = 0;
    __syncthreads();
    for (int j = tid; j < cntE; j += 1024)
        atomicAdd(&cnt[buf[bstart + j] & (CB_NODES - 1)], 1);
    __syncthreads();

    int v = cnt[tid];
    s[tid] = v;
    __syncthreads();
    for (int o = 1; o < CB_NODES; o <<= 1) {
        int y = (tid >= o) ? s[tid - o] : 0;
        __syncthreads();
        s[tid] += y;
        __syncthreads();
    }
    int excl = s[tid] - v;
    int d = d0 + tid;
    if (d < n) { rs[d] = cb + excl; deg[d] = v; }

    pos[tid] = 0;
    cnt[tid] = excl;   // repurpose: per-dst exclusive base
    __syncthreads();

    for (int j = tid; j < cntE; j += 1024) {
        unsigned pk = buf[bstart + j];
        int li = pk & (CB_NODES - 1);
        int src = (int)(pk >> CB_SHIFT);
        int p = cb + cnt[li] + atomicAdd(&pos[li], 1);
        csr[p] = src;
    }
}

// ---------------------------------------------------------------------------
// W pre-pack (unchanged)
// ---------------------------------------------------------------------------
__global__ __launch_bounds__(256) void pack_w_kernel(
        const float* __restrict__ WsA, const float* __restrict__ WsP,
        const float* __restrict__ Wa2p, const float* __restrict__ Wp2a,
        unsigned short* __restrict__ Bpack) {
    int combo = blockIdx.x >> 4;
    int e = (blockIdx.x & 15) * 256 + threadIdx.x;   // 0..4095
    int layer = combo >> 1;
    const float* Ws = ((combo & 1) ? WsP : WsA) + (size_t)layer * D * D;
    const float* Wm = ((combo & 1) ? Wa2p : Wp2a) + (size_t)layer * D * D;

    int f = e >> 6, lane = e & 63;
    int nf = f >> 3, ks = f & 7;
    int k0 = ks * 32 + (lane >> 4) * 8;
    int col = nf * 16 + (lane & 15);

    unsigned short v[8];
#pragma unroll
    for (int j = 0; j < 8; ++j) {
        int k = k0 + j;
        float x = (k < D) ? Ws[(size_t)k * D + col] : Wm[(size_t)(k - D) * D + col];
        v[j] = f2bf(x);
    }
    uint4 o;
    o.x = v[0] | ((unsigned)v[1] << 16);
    o.y = v[2] | ((unsigned)v[3] << 16);
    o.z = v[4] | ((unsigned)v[5] << 16);
    o.w = v[6] | ((unsigned)v[7] << 16);
    *(uint4*)(Bpack + (size_t)combo * 32768 + (size_t)e * 8) = o;
}

// ---------------------------------------------------------------------------
// bf16 pull-aggregation, BOTH directions in one launch.
// VALU diet: hi-half accumulates UNMASKED (as_float(v) keeps the low 16 bits
// as <=2^-9 relative noise — same order as bf16 quantization, threshold has
// 3x headroom). Saves the 4 AND ops per 16B: inner loop 16 -> 12 VALU.
// ---------------------------------------------------------------------------
__global__ __launch_bounds__(256) void aggregate_duo(
        const unsigned short* __restrict__ srcA, const int* __restrict__ rsA,
        const int* __restrict__ csrA, int nA, unsigned short* __restrict__ aggA,
        const unsigned short* __restrict__ srcP, const int* __restrict__ rsP,
        const int* __restrict__ csrP, int nP, unsigned short* __restrict__ aggP) {
    int gw   = (blockIdx.x * 256 + threadIdx.x) >> 6;
    int lane = threadIdx.x & 63;
    int sub  = lane >> 4;
    int sl   = lane & 15;

    const unsigned short* xsrc; const int* rs; const int* csr;
    unsigned short* agg; int d;
    if (gw < nA) { d = gw;      xsrc = srcA; rs = rsA; csr = csrA; agg = aggA; }
    else {
        d = gw - nA;
        if (d >= nP) return;
        xsrc = srcP; rs = rsP; csr = csrP; agg = aggP;
    }

    int s0 = rs[d], s1 = rs[d + 1];
    float acc[8] = {0.f, 0.f, 0.f, 0.f, 0.f, 0.f, 0.f, 0.f};
    for (int j = s0 + sub; j < s1; j += 4) {
        int s = csr[j];
        uint4 v = *(const uint4*)(xsrc + (size_t)s * D + sl * 8);
        acc[0] += bflo(v.x); acc[1] += __uint_as_float(v.x);
        acc[2] += bflo(v.y); acc[3] += __uint_as_float(v.y);
        acc[4] += bflo(v.z); acc[5] += __uint_as_float(v.z);
        acc[6] += bflo(v.w); acc[7] += __uint_as_float(v.w);
    }
#pragma unroll
    for (int i = 0; i < 8; ++i) {
        acc[i] += __shfl_xor(acc[i], 16);
        acc[i] += __shfl_xor(acc[i], 32);
    }
    if (sub == 0) {
        uint4 o;
        o.x = f2bf(acc[0]) | ((unsigned)f2bf(acc[1]) << 16);
        o.y = f2bf(acc[2]) | ((unsigned)f2bf(acc[3]) << 16);
        o.z = f2bf(acc[4]) | ((unsigned)f2bf(acc[5]) << 16);
        o.w = f2bf(acc[6]) | ((unsigned)f2bf(acc[7]) << 16);
        *(uint4*)(agg + (size_t)d * D + sl * 8) = o;
    }
}

// ---------------------------------------------------------------------------
// MFMA node update, column-split (unchanged from round 10 — verified win)
// ---------------------------------------------------------------------------
__global__ __launch_bounds__(256) void linear_mfma_duo(
        const unsigned short* __restrict__ xsA, const unsigned short* __restrict__ xmA,
        const unsigned short* __restrict__ BpA, const float* __restrict__ bsA,
        const float* __restrict__ bmA, const int* __restrict__ degA_, int nA,
        unsigned short* __restrict__ outA, int gmA,
        const unsigned short* __restrict__ xsP, const unsigned short* __restrict__ xmP,
        const unsigned short* __restrict__ BpP, const float* __restrict__ bsP,
        const float* __restrict__ bmP, const int* __restrict__ degP_, int nP,
        unsigned short* __restrict__ outP, int relu) {
    __shared__ uint4 lds4[2048];   // 32 KB: [64][256] bf16 swizzled
    unsigned char* lds = (unsigned char*)lds4;
    int tid = threadIdx.x;
    int wave = tid >> 6, lane = tid & 63;

    const unsigned short *xs, *xm, *Bpack; const float *bs, *bm;
    const int* deg; int n; unsigned short* out;
    int b = blockIdx.x;
    if (b < gmA) { xs = xsA; xm = xmA; Bpack = BpA; bs = bsA; bm = bmA;
                   deg = degA_; n = nA; out = outA; }
    else { b -= gmA; xs = xsP; xm = xmP; Bpack = BpP; bs = bsP; bm = bmP;
           deg = degP_; n = nP; out = outP; }
    int r_base = b * 64;

    // ---- load this wave's B slice (cols 32w..32w+31): 16 fragments, once ----
    const bf16x8_t* bp = (const bf16x8_t*)Bpack;
    bf16x8_t bb[2][8];
#pragma unroll
    for (int nf2 = 0; nf2 < 2; ++nf2)
#pragma unroll
        for (int ks = 0; ks < 8; ++ks)
            bb[nf2][ks] = bp[((wave * 2 + nf2) * 8 + ks) * 64 + lane];

    // ---- stage [xs|xm] tile: 2048 16B chunks, 8 per thread ----
#pragma unroll
    for (int i = 0; i < 8; ++i) {
        int c = i * 256 + tid;        // 0..2047
        int row = c >> 5;             // 0..63
        int kc = (c & 31) * 8;        // bf16 elem offset 0..248
        int rg = r_base + row;
        uint4 w = make_uint4(0, 0, 0, 0);
        if (rg < n) {
            const unsigned short* src = (kc < D) ? (xs + (size_t)rg * D + kc)
                                                 : (xm + (size_t)rg * D + (kc - D));
            w = *(const uint4*)src;
        }
        unsigned addr = ((unsigned)(row * 512 + kc * 2)) ^ ((unsigned)((row & 7) << 4));
        *(uint4*)(lds + addr) = w;
    }
    __syncthreads();

    // ---- row sub-tile loop: a from LDS, 16 MFMAs per rt ----
    f32x4_t acc[4][2];
#pragma unroll
    for (int rt = 0; rt < 4; ++rt)
#pragma unroll
        for (int nf2 = 0; nf2 < 2; ++nf2) acc[rt][nf2] = (f32x4_t){0.f, 0.f, 0.f, 0.f};

#pragma unroll
    for (int rt = 0; rt < 4; ++rt) {
        int lrow = rt * 16 + (lane & 15);
        bf16x8_t a[8];
#pragma unroll
        for (int ks = 0; ks < 8; ++ks) {
            unsigned addr = ((unsigned)(lrow * 512 + ks * 64 + (lane >> 4) * 16))
                            ^ ((unsigned)((lrow & 7) << 4));
            a[ks] = *(const bf16x8_t*)(lds + addr);
        }
#pragma unroll
        for (int ks = 0; ks < 8; ++ks) {
            acc[rt][0] = __builtin_amdgcn_mfma_f32_16x16x32_bf16(a[ks], bb[0][ks], acc[rt][0], 0, 0, 0);
            acc[rt][1] = __builtin_amdgcn_mfma_f32_16x16x32_bf16(a[ks], bb[1][ks], acc[rt][1], 0, 0, 0);
        }
    }

    // ---- epilogue: wave w writes cols [32w,32w+32) for all 64 rows ----
#pragma unroll
    for (int nf2 = 0; nf2 < 2; ++nf2) {
        int col = wave * 32 + nf2 * 16 + (lane & 15);
        float bsv = bs[col], bmv = bm[col];
#pragma unroll
        for (int rt = 0; rt < 4; ++rt) {
            int rb2 = r_base + rt * 16 + (lane >> 4) * 4;
#pragma unroll
            for (int rr = 0; rr < 4; ++rr) {
                int r = rb2 + rr;
                if (r < n) {
                    float dgv = (float)deg[r];
                    float v = acc[rt][nf2][rr] + bsv + dgv * bmv;
                    if (relu) v = fmaxf(v, 0.f);
                    out[(size_t)r * D + col] = f2bf(v);
                }
            }
        }
    }
}

// ---------------------------------------------------------------------------
// supervision dot products on bf16 embeddings
// ---------------------------------------------------------------------------
__global__ __launch_bounds__(256) void dot_kernel(
        const unsigned short* __restrict__ za, const unsigned short* __restrict__ zp,
        const int* __restrict__ sa, const int* __restrict__ sp, int S,
        float* __restrict__ out) {
    int gw   = (blockIdx.x * 256 + threadIdx.x) >> 6;
    int lane = threadIdx.x & 63;
    int nw   = (gridDim.x * 256) >> 6;
    for (int i = gw; i < S; i += nw) {
        int a = sa[i], p = sp[i];
        unsigned ua = *(const unsigned*)(za + (size_t)a * D + lane * 2);
        unsigned up = *(const unsigned*)(zp + (size_t)p * D + lane * 2);
        float s = bflo(ua) * bflo(up)
                + __uint_as_float(ua & 0xffff0000u) * __uint_as_float(up & 0xffff0000u);
#pragma unroll
        for (int off = 32; off > 0; off >>= 1) s += __shfl_xor(s, off);
        if (lane == 0) out[i] = s;
    }
}

// ---------------------------------------------------------------------------
extern "C" void kernel_launch(void* const* d_in, const int* in_sizes, int n_in,
                              void* d_out, int out_size, void* d_ws, size_t ws_size,
                              hipStream_t stream) {
    const float* x_a  = (const float*)d_in[0];
    const float* x_p  = (const float*)d_in[1];
    const int*   ea   = (const int*)d_in[2];
    const int*   ep   = (const int*)d_in[3];
    const int*   sa   = (const int*)d_in[4];
    const int*   sp   = (const int*)d_in[5];
    const float* WsA  = (const float*)d_in[6];
    const float* bsA  = (const float*)d_in[7];
    const float* WsP  = (const float*)d_in[8];
    const float* bsP  = (const float*)d_in[9];
    const float* Wa2p = (const float*)d_in[10];
    const float* ba2p = (const float*)d_in[11];
    const float* Wp2a = (const float*)d_in[12];
    const float* bp2a = (const float*)d_in[13];

    const int nA = in_sizes[0] / D;   // 100000
    const int nP = in_sizes[1] / D;   // 200000
    const int E  = in_sizes[2];       // 600000
    const int S  = in_sizes[4];       // 100000

    // ---- workspace layout ----
    char* ws = (char*)d_ws;
    size_t curoff = 0;
    auto alloc = [&](size_t bytes) -> void* {
        void* p = ws + curoff;
        curoff = (curoff + bytes + 255) & ~(size_t)255;
        return p;
    };
    unsigned short* xb_a  = (unsigned short*)alloc((size_t)nA * D * 2);
    unsigned short* xb_p  = (unsigned short*)alloc((size_t)nP * D * 2);
    unsigned short* agg_a = (unsigned short*)alloc((size_t)nA * D * 2);
    unsigned short* agg_p = (unsigned short*)alloc((size_t)nP * D * 2);
    unsigned short* y_a   = (unsigned short*)alloc((size_t)nA * D * 2);
    unsigned short* y_p   = (unsigned short*)alloc((size_t)nP * D * 2);
    unsigned short* z_a   = (unsigned short*)alloc((size_t)nA * D * 2);
    unsigned short* z_p   = (unsigned short*)alloc((size_t)nP * D * 2);
    int* degA = (int*)alloc((size_t)nA * 4);
    int* degP = (int*)alloc((size_t)nP * 4);
    int* rsA  = (int*)alloc(((size_t)nA + 1) * 4);
    int* rsP  = (int*)alloc(((size_t)nP + 1) * 4);
    int* csrA = (int*)alloc((size_t)E * 4);
    int* csrP = (int*)alloc((size_t)E * 4);
    unsigned short* Bpack = (unsigned short*)alloc((size_t)4 * 32768 * 2);  // 256 KB

    // preprocessing scratch aliases z_a/z_p (done before layer-1 writes z)
    const int nbcA = (nA + CB_NODES - 1) >> CB_SHIFT;   // 98
    const int nbcP = (nP + CB_NODES - 1) >> CB_SHIFT;   // 196
    const int NBC  = nbcA + nbcP;                       // 294
    unsigned* buf = (unsigned*)z_a;           // 2E*4 = 4.8 MB
    int* gcur  = (int*)z_p;                   // NBC_MAX ints
    int* cbase = gcur + NBC_MAX;
    int* chist = cbase + NBC_MAX;

    const int nchunk = (E + CHE - 1) / CHE;   // 293

    // ---- bf16 input copies + graph preprocessing + W packing ----
    f32_to_bf16_duo<<<3072, 256, 0, stream>>>(x_a, xb_a, nA * D / 8,
                                              x_p, xb_p, nP * D / 8);
    hipMemsetAsync(chist, 0, NBC_MAX * 4, stream);
    pack_w_kernel<<<64, 256, 0, stream>>>(WsA, WsP, Wa2p, Wp2a, Bpack);
    coarse_count_kernel<<<nchunk, 256, 0, stream>>>(ea, ep, E, nbcA, NBC, chist);
    coarse_scan_kernel<<<1, NBC_MAX, 0, stream>>>(chist, nbcA, NBC, E,
                                                  gcur, cbase, rsA + nA, rsP + nP);
    multisplit_kernel<<<nchunk, 512, 0, stream>>>(ea, ep, E, nbcA, gcur, buf);
    fine_csr_kernel<<<NBC, 1024, 0, stream>>>(buf, E, nbcA, cbase, chist,
                                              rsA, degA, csrA, nA,
                                              rsP, degP, csrP, nP);

    const int gmA = (nA + 63) / 64;   // 1563
    const int gmP = (nP + 63) / 64;   // 3125
    const int gAgg = (nA + nP + 3) / 4;

    // ---- layer 0 (relu) ----
    aggregate_duo<<<gAgg, 256, 0, stream>>>(xb_p, rsA, csrA, nA, agg_a,
                                            xb_a, rsP, csrP, nP, agg_p);
    linear_mfma_duo<<<gmA + gmP, 256, 0, stream>>>(
        xb_a, agg_a, Bpack + 0 * 32768, bsA, bp2a, degA, nA, y_a, gmA,
        xb_p, agg_p, Bpack + 1 * 32768, bsP, ba2p, degP, nP, y_p, 1);

    // ---- layer 1 (no relu) ----
    aggregate_duo<<<gAgg, 256, 0, stream>>>(y_p, rsA, csrA, nA, agg_a,
                                            y_a, rsP, csrP, nP, agg_p);
    linear_mfma_duo<<<gmA + gmP, 256, 0, stream>>>(
        y_a, agg_a, Bpack + 2 * 32768, bsA + D, bp2a + D, degA, nA, z_a, gmA,
        y_p, agg_p, Bpack + 3 * 32768, bsP + D, ba2p + D, degP, nP, z_p, 0);

    // ---- supervision scores ----
    dot_kernel<<<(S + 3) / 4, 256, 0, stream>>>(z_a, z_p, sa, sp, S, (float*)d_out);
}